// Round 7
// baseline (742.104 us; speedup 1.0000x reference)
//
#include <hip/hip_runtime.h>
#include <hip/hip_bf16.h>
#include <math.h>

// Problem constants
#define BB 2
#define SS 2048
#define DD 2048
#define HH 32
#define HDD 64
#define MBB 16
#define NN 128

typedef unsigned short u16;
typedef short bf16x8_t __attribute__((ext_vector_type(8)));
typedef short bf16x4_t __attribute__((ext_vector_type(4)));
typedef float f32x4_t __attribute__((ext_vector_type(4)));

__device__ __forceinline__ float b2f(u16 u) { return __uint_as_float(((unsigned)u) << 16); }
__device__ __forceinline__ u16 f2b(float f) {
    unsigned u = __float_as_uint(f);
    return (u16)((u + 0x7FFFu + ((u >> 16) & 1u)) >> 16);
}
__device__ __forceinline__ unsigned pk2(float a, float b) {
    return (unsigned)f2b(a) | ((unsigned)f2b(b) << 16);
}
// HW packed f32->bf16 (RNE, same rounding as f2b)
__device__ __forceinline__ unsigned cvtpk(float lo, float hi) {
    unsigned r;
    asm("v_cvt_pk_bf16_f32 %0, %1, %2" : "=v"(r) : "v"(lo), "v"(hi));
    return r;
}
__device__ __forceinline__ unsigned pk2r(u16 a, u16 b) { return (unsigned)a | ((unsigned)b << 16); }
__device__ __forceinline__ bf16x4_t mk4(unsigned lo, unsigned hi) {
    union { unsigned u[2]; bf16x4_t v; } t;
    t.u[0] = lo;
    t.u[1] = hi;
    return t.v;
}
// K=16 bf16 MFMA (gfx90a+ "1k" builtin, supported on gfx950).
// A/B frag: [row=lane&15][k=quad*4+j] — coincides with our C-layout residency.
#define MFMA16(A, B, C) __builtin_amdgcn_mfma_f32_16x16x16bf16_1k((A), (B), (C), 0, 0, 0)

__device__ __forceinline__ float wsum(float x) {
    x += __shfl_xor(x, 32);
    x += __shfl_xor(x, 16);
    x += __shfl_xor(x, 8);
    x += __shfl_xor(x, 4);
    x += __shfl_xor(x, 2);
    x += __shfl_xor(x, 1);
    return x;
}

// DPP-based 16-lane row reduction (pure VALU, bit-identical to xor1/2/4/8 tree)
template <int CTRL>
__device__ __forceinline__ float dppadd(float x) {
    int t = __builtin_amdgcn_update_dpp(0, __float_as_int(x), CTRL, 0xF, 0xF, true);
    return x + __int_as_float(t);
}
__device__ __forceinline__ float rsum16(float x) {
    x = dppadd<0xB1>(x);   // quad_perm [1,0,3,2]  = xor1
    x = dppadd<0x4E>(x);   // quad_perm [2,3,0,1]  = xor2
    x = dppadd<0x141>(x);  // row_half_mirror
    x = dppadd<0x140>(x);  // row_mirror
    return x;
}

typedef __attribute__((address_space(3))) unsigned int lds_u32;
typedef __attribute__((address_space(1))) const unsigned int glb_u32;
__device__ __forceinline__ void async_copy16(const void* g, void* l) {
    __builtin_amdgcn_global_load_lds((glb_u32*)g, (lds_u32*)l, 16, 0, 0);
}

// within-head permutation: perm(d) = (d&15)*4 + (d>>4);  inverse: d = (j>>2) + (j&3)*16

// ---------------- fused fp32 -> bf16 for x + 4 weight matrices ----------------
__global__ __launch_bounds__(256) void k_cvt5(const float* __restrict__ x, const float* __restrict__ wq,
                                              const float* __restrict__ wk, const float* __restrict__ wv,
                                              const float* __restrict__ wo, u16* __restrict__ xb,
                                              u16* __restrict__ wqb, u16* __restrict__ wkb,
                                              u16* __restrict__ wvb, u16* __restrict__ wob) {
    int sl = blockIdx.y;
    long e = (long)(blockIdx.x * 256 + threadIdx.x) * 4;
    if (sl == 5) {
        long n = e >> 11;
        int cin = (int)(e & 2047);
        int hd0 = (cin >> 6) * 64 + ((cin & 63) >> 2);
        const float* src = wo + n * 2048 + hd0;
        float f0 = src[0], f1 = src[16], f2 = src[32], f3 = src[48];
        uint2 o;
        o.x = pk2(f0, f1);
        o.y = pk2(f2, f3);
        *(uint2*)(wob + e) = o;
        return;
    }
    const float* s;
    u16* d;
    if (sl == 0) { s = x; d = xb; }
    else if (sl == 1) { s = x + 4194304; d = xb + 4194304; }
    else if (sl == 2) { s = wq; d = wqb; }
    else if (sl == 3) { s = wk; d = wkb; }
    else { s = wv; d = wvb; }
    float4 f = *(const float4*)(s + e);
    uint2 o;
    o.x = pk2(f.x, f.y);
    o.y = pk2(f.z, f.w);
    *(uint2*)(d + e) = o;
}

// ---------------- cos/sin tables ----------------
__global__ void k_trig(const float* __restrict__ pf, float* __restrict__ ct, float* __restrict__ st) {
    int i = blockIdx.x * 256 + threadIdx.x;  // 65536 = S*32
    float f = pf[i];
    ct[i] = cosf(f);
    st[i] = sinf(f);
}

// ---------------- permuted post-LN gamma/beta ----------------
__global__ void k_ppg(const float* __restrict__ pg, const float* __restrict__ pb,
                      float* __restrict__ pgp, float* __restrict__ pbp) {
    int i = blockIdx.x * 256 + threadIdx.x;  // 2048
    int h = i >> 6, o = i & 63;
    int src = h * 64 + (o >> 2) + (o & 3) * 16;
    pgp[i] = pg[src];
    pbp[i] = pb[src];
}

// ---------------- bf16 MFMA GEMM:  C[M,N] = A[M,K] * B[N,K]^T ----------------
template <int EPI>
__global__ __launch_bounds__(256) void k_gemm_bt(const u16* __restrict__ A, const u16* __restrict__ B0,
                                                 const u16* __restrict__ B1, const u16* __restrict__ B2,
                                                 void* __restrict__ C0, void* __restrict__ C1,
                                                 void* __restrict__ C2, int M, int Nn, int K,
                                                 const float* __restrict__ ct, const float* __restrict__ st) {
    __shared__ u16 As[128 * 32];
    __shared__ u16 Bs[128 * 32];
    int z = blockIdx.z;
    const u16* Bm = (z == 0) ? B0 : (z == 1) ? B1 : B2;
    void* Cout = (z == 0) ? C0 : (z == 1) ? C1 : C2;
    int tid = threadIdx.x, lane = tid & 63, wv = tid >> 6;
    int m0 = blockIdx.y * 128, n0 = blockIdx.x * 128;
    int wm = wv >> 1, wn = wv & 1;

    f32x4_t acc[4][4];
    f32x4_t zero = {0.f, 0.f, 0.f, 0.f};
#pragma unroll
    for (int a = 0; a < 4; ++a)
#pragma unroll
        for (int b = 0; b < 4; ++b) acc[a][b] = zero;

    int mrow = lane & 15, qk = (lane >> 4) * 8;
    const int kTiles = K >> 5;
    for (int kt = 0; kt < kTiles; ++kt) {
        __syncthreads();
        int kb = kt << 5;
#pragma unroll
        for (int it = 0; it < 2; ++it) {
            int cb = it * 256 + wv * 64;  // wave-uniform chunk base
            int c = cb + lane;
            const u16* gpA = A + (m0 + (c >> 2)) * K + kb + ((c & 3) << 3);
            async_copy16(gpA, &As[cb << 3]);
            const u16* gpB = Bm + (n0 + (c >> 2)) * K + kb + ((c & 3) << 3);
            async_copy16(gpB, &Bs[cb << 3]);
        }
        asm volatile("s_waitcnt vmcnt(0)" ::: "memory");
        __syncthreads();

        bf16x8_t af[4], bfr[4];
#pragma unroll
        for (int mi = 0; mi < 4; ++mi)
            af[mi] = *(const bf16x8_t*)&As[(wm * 64 + mi * 16 + mrow) * 32 + qk];
#pragma unroll
        for (int ni = 0; ni < 4; ++ni)
            bfr[ni] = *(const bf16x8_t*)&Bs[(wn * 64 + ni * 16 + mrow) * 32 + qk];
#pragma unroll
        for (int mi = 0; mi < 4; ++mi)
#pragma unroll
            for (int ni = 0; ni < 4; ++ni)
                acc[mi][ni] = __builtin_amdgcn_mfma_f32_16x16x32_bf16(af[mi], bfr[ni], acc[mi][ni], 0, 0, 0);
    }

    int col16 = lane & 15, rq = (lane >> 4) * 4;
#pragma unroll
    for (int mi = 0; mi < 4; ++mi) {
#pragma unroll
        for (int ni = 0; ni < 4; ++ni) {
#pragma unroll
            for (int r = 0; r < 4; ++r) {
                int gr = m0 + wm * 64 + mi * 16 + rq + r;
                int gc = n0 + wn * 64 + ni * 16 + col16;
                float val = acc[mi][ni][r];
                if (EPI == 0) {
                    ((float*)Cout)[gr * Nn + gc] = val;
                } else {
                    // fused RoPE: pair partner sits on lane^1 (gc differs in bit 0)
                    int b = gr >> 11, s2 = gr & 2047, hh = gc >> 6, hd = gc & 63;
                    int fi = s2 * 32 + (hd >> 1);
                    float c = ct[fi], sn = st[fi];
                    float partner = __shfl_xor(val, 1);
                    float y = (gc & 1) ? (partner * sn + val * c) : (val * c - partner * sn);
                    int po = (z == 2) ? ((hd & 15) * 4 + (hd >> 4)) : hd;  // V stored permuted
                    ((u16*)Cout)[(((b * HH + hh) * SS) + s2) * HDD + po] = f2b(y);
                }
            }
        }
    }
}

// ---------------- ilr gate ----------------
__global__ __launch_bounds__(256) void k_lr(const u16* __restrict__ xb, const float* __restrict__ ilrW,
                                            const float* __restrict__ ilrb, float* __restrict__ lrout) {
    __shared__ u16 xr[4][2048];
    int row0 = blockIdx.x * 4;
    int tid = threadIdx.x, lane = tid & 63, wv = tid >> 6;
    const unsigned* src = (const unsigned*)(xb + row0 * 2048);
    unsigned* dst = (unsigned*)xr;
    for (int i = tid; i < 4096; i += 256) dst[i] = src[i];
    __syncthreads();
    int b = row0 >> 11, s0 = row0 & 2047;
#pragma unroll
    for (int sub = 0; sub < 8; ++sub) {
        int h = wv * 8 + sub;
        const float* wp = ilrW + h * 2048;
        float a0 = 0.f, a1 = 0.f, a2 = 0.f, a3 = 0.f;
        for (int i = 0; i < 16; ++i) {
            int idx = i * 128 + lane * 2;
            float2 w2 = *(const float2*)(wp + idx);
            unsigned p0 = *(const unsigned*)&xr[0][idx];
            unsigned p1 = *(const unsigned*)&xr[1][idx];
            unsigned p2 = *(const unsigned*)&xr[2][idx];
            unsigned p3 = *(const unsigned*)&xr[3][idx];
            a0 += b2f((u16)p0) * w2.x + b2f((u16)(p0 >> 16)) * w2.y;
            a1 += b2f((u16)p1) * w2.x + b2f((u16)(p1 >> 16)) * w2.y;
            a2 += b2f((u16)p2) * w2.x + b2f((u16)(p2 >> 16)) * w2.y;
            a3 += b2f((u16)p3) * w2.x + b2f((u16)(p3 >> 16)) * w2.y;
        }
        a0 = wsum(a0);
        a1 = wsum(a1);
        a2 = wsum(a2);
        a3 = wsum(a3);
        if (lane == 0) {
            float bv = ilrb[h];
            float* op = lrout + ((b * HH + h) * SS) + s0;
            op[0] = (1.0f / (1.0f + expf(-(a0 + bv)))) * (1.0f / 64.0f);
            op[1] = (1.0f / (1.0f + expf(-(a1 + bv)))) * (1.0f / 64.0f);
            op[2] = (1.0f / (1.0f + expf(-(a2 + bv)))) * (1.0f / 64.0f);
            op[3] = (1.0f / (1.0f + expf(-(a3 + bv)))) * (1.0f / 64.0f);
        }
    }
}

// ---------------- TTT scan: ONE WAVE per (b,h) ----------------
// K=16 matmuls (dW = XKT@G, Pu@G) on mfma_f32_16x16x16bf16_1k whose A/B fragment
// layout [row=lane&15][k=quad*4+j] coincides with C-layout register residency ->
// XKT/GST/PUL LDS buffers deleted. Attn computed TRANSPOSED (mfma(ka,qa)) so the
// Pu A-frag is lane-local. W update accumulates in the MFMA C operand (lr
// pre-scaled by -gs15; PV compensated by ratio4 = gs4/gs15); bb folded into the
// Z/XQW MFMA C-init. Only WbL (W f32->bf16 transpose for next step) stays in LDS.
__global__ __launch_bounds__(64, 1) void k_scan(const u16* __restrict__ qb, const u16* __restrict__ kb2,
                                                const u16* __restrict__ vc, const float* __restrict__ lrbuf,
                                                const float* __restrict__ lgs, const float* __restrict__ tg,
                                                const float* __restrict__ tb, const float* __restrict__ W0,
                                                const float* __restrict__ b0, u16* __restrict__ ys) {
    __shared__ u16 WbL[64 * 72];  // [d2][d1] bf16 W for next step's B-frags

    const int bh = blockIdx.x, h = bh & 31, b = bh >> 5;
    const int lane = threadIdx.x & 63;
    const int quad = lane >> 4, col = lane & 15;
    const int base = bh * SS;

    float gd4[4], bd4[4], bbv[4], g2[4], gb[4];
#pragma unroll
    for (int tn = 0; tn < 4; ++tn) {
        gd4[tn] = tg[h * 64 + tn * 16 + col];
        bd4[tn] = tb[h * 64 + tn * 16 + col];
        bbv[tn] = b0[h * 64 + tn * 16 + col];
        g2[tn] = gd4[tn] * gd4[tn];
        gb[tn] = gd4[tn] * bd4[tn];
    }
    float G2m;  // mean over d of gamma^2
    {
        float s = g2[0] + g2[1] + g2[2] + g2[3];
        s = rsum16(s);
        G2m = s * (1.f / 64.f);
    }
    const float gs15 = fmaxf(1.f / 16.f + lgs[15], 0.f);
    const float inv15 = gs15 > 0.f ? 1.f / gs15 : 0.f;
    float gs4[4], ratio4[4];
#pragma unroll
    for (int r = 0; r < 4; ++r) {
        int i = quad * 4 + r;
        gs4[r] = fmaxf(1.f / (float)(i + 1) + lgs[i], 0.f);
        ratio4[r] = gs4[r] * inv15;
    }

    f32x4_t Wc[4][4];
#pragma unroll
    for (int tm = 0; tm < 4; ++tm)
#pragma unroll
        for (int tn = 0; tn < 4; ++tn)
#pragma unroll
            for (int r = 0; r < 4; ++r)
                Wc[tm][tn][r] = W0[h * 4096 + (tm * 16 + quad * 4 + r) * 64 + tn * 16 + col];

    {  // initial Wb
        unsigned* wb32 = (unsigned*)WbL;
#pragma unroll
        for (int tn = 0; tn < 4; ++tn)
#pragma unroll
            for (int tm = 0; tm < 4; ++tm) {
                int a = (tn * 16 + col) * 36 + tm * 8 + quad * 2;  // u32 units; row stride 36 u32
                wb32[a] = cvtpk(Wc[tm][tn][0], Wc[tm][tn][1]);
                wb32[a + 1] = cvtpk(Wc[tm][tn][2], Wc[tm][tn][3]);
            }
    }

    // prefetch chunk 0 (lr pre-scaled by -gs15)
    bf16x8_t ka[2], qa[2];
    float lr4[4];
    u16 kraw[16], vraw[16], qraw[16];
    {
        const u16* kp = kb2 + (base + col) * 64;
        const u16* qp = qb + (base + col) * 64;
#pragma unroll
        for (int kh = 0; kh < 2; ++kh) {
            ka[kh] = *(const bf16x8_t*)(kp + kh * 32 + quad * 8);
            qa[kh] = *(const bf16x8_t*)(qp + kh * 32 + quad * 8);
        }
#pragma unroll
        for (int r = 0; r < 4; ++r) lr4[r] = -gs15 * lrbuf[base + quad * 4 + r];
#pragma unroll
        for (int tn = 0; tn < 4; ++tn)
#pragma unroll
            for (int r = 0; r < 4; ++r) {
                int idx = (base + quad * 4 + r) * 64 + tn * 16 + col;
                kraw[tn * 4 + r] = kb2[idx];
                qraw[tn * 4 + r] = qb[idx];
            }
#pragma unroll
        for (int r = 0; r < 4; ++r) {
            long ro = (long)(base + quad * 4 + r) * 64 + col * 4;
            ushort4 tv = *(const ushort4*)(vc + ro);
            vraw[r] = tv.x; vraw[4 + r] = tv.y; vraw[8 + r] = tv.z; vraw[12 + r] = tv.w;
        }
    }

    // prologue: wbf(0) read
    bf16x8_t wbf[4][2];
#pragma unroll
    for (int tn = 0; tn < 4; ++tn)
#pragma unroll
        for (int kh = 0; kh < 2; ++kh)
            wbf[tn][kh] = *(const bf16x8_t*)&WbL[(tn * 16 + col) * 72 + kh * 32 + quad * 8];

    const f32x4_t zf = {0.f, 0.f, 0.f, 0.f};

    for (int n = 0; n < NN; ++n) {
        const int s0 = n * 16;

        // Z = XK@W + bb, XQW = XQ@W + bb (bb as MFMA C-init), AttnT = XK@XQ^T
        f32x4_t z[4], xqw[4], attnT;
#pragma unroll
        for (int tn = 0; tn < 4; ++tn) {
            f32x4_t cb = {bbv[tn], bbv[tn], bbv[tn], bbv[tn]};
            z[tn] = __builtin_amdgcn_mfma_f32_16x16x32_bf16(ka[1], wbf[tn][1], cb, 0, 0, 0);
            z[tn] = __builtin_amdgcn_mfma_f32_16x16x32_bf16(ka[0], wbf[tn][0], z[tn], 0, 0, 0);
            xqw[tn] = __builtin_amdgcn_mfma_f32_16x16x32_bf16(qa[1], wbf[tn][1], cb, 0, 0, 0);
            xqw[tn] = __builtin_amdgcn_mfma_f32_16x16x32_bf16(qa[0], wbf[tn][0], xqw[tn], 0, 0, 0);
        }
        attnT = __builtin_amdgcn_mfma_f32_16x16x32_bf16(ka[1], qa[1], zf, 0, 0, 0);
        attnT = __builtin_amdgcn_mfma_f32_16x16x32_bf16(ka[0], qa[0], attnT, 0, 0, 0);

        // lane holds Attn[i=col][j=quad*4+r]; tril mask j<=i, in-register Pu A-frag
        float pv0 = (quad * 4 + 0 <= col) ? (1.f + attnT[0]) : 0.f;
        float pv1 = (quad * 4 + 1 <= col) ? (1.f + attnT[1]) : 0.f;
        float pv2 = (quad * 4 + 2 <= col) ? (1.f + attnT[2]) : 0.f;
        float pv3 = (quad * 4 + 3 <= col) ? (1.f + attnT[3]) : 0.f;
        bf16x4_t pa4 = mk4(cvtpk(pv0, pv1), cvtpk(pv2, pv3));

        // prefetch next chunk (clamped on last iter)
        bf16x8_t nka[2], nqa[2];
        float nlr[4];
        u16 nkraw[16], nvraw[16], nqraw[16];
        {
            const int sp = (n + 1 < NN) ? s0 + 16 : s0;
            const u16* kp = kb2 + (base + sp + col) * 64;
            const u16* qp = qb + (base + sp + col) * 64;
#pragma unroll
            for (int kh = 0; kh < 2; ++kh) {
                nka[kh] = *(const bf16x8_t*)(kp + kh * 32 + quad * 8);
                nqa[kh] = *(const bf16x8_t*)(qp + kh * 32 + quad * 8);
            }
#pragma unroll
            for (int r = 0; r < 4; ++r) nlr[r] = -gs15 * lrbuf[base + sp + quad * 4 + r];
#pragma unroll
            for (int tn = 0; tn < 4; ++tn)
#pragma unroll
                for (int r = 0; r < 4; ++r) {
                    int idx = (base + sp + quad * 4 + r) * 64 + tn * 16 + col;
                    nkraw[tn * 4 + r] = kb2[idx];
                    nqraw[tn * 4 + r] = qb[idx];
                }
#pragma unroll
            for (int r = 0; r < 4; ++r) {
                long ro = (long)(base + sp + quad * 4 + r) * 64 + col * 4;
                ushort4 tv = *(const ushort4*)(vc + ro);
                nvraw[r] = tv.x; nvraw[4 + r] = tv.y; nvraw[8 + r] = tv.z; nvraw[12 + r] = tv.w;
            }
        }

        // fused ln_l2_bwd: single DPP reduce phase over 6 sums (z already includes bb)
        float c1[16];
        float A1[4], A2[4], A3[4], A4[4], A5[4], A6[4];
#pragma unroll
        for (int r = 0; r < 4; ++r) { A1[r] = 0.f; A2[r] = 0.f; A3[r] = 0.f; A4[r] = 0.f; A5[r] = 0.f; A6[r] = 0.f; }
#pragma unroll
        for (int tn = 0; tn < 4; ++tn)
#pragma unroll
            for (int r = 0; r < 4; ++r) {
                float zv = z[tn][r];
                float tgt = b2f(vraw[tn * 4 + r]) - b2f(kraw[tn * 4 + r]);
                float c = gb[tn] - gd4[tn] * tgt;  // g*(b - tgt)
                c1[tn * 4 + r] = c;
                float t = g2[tn] * zv;
                A1[r] += zv;
                A2[r] = fmaf(zv, zv, A2[r]);
                A3[r] += t;
                A4[r] = fmaf(t, zv, A4[r]);
                A5[r] = fmaf(c, zv, A5[r]);
                A6[r] += c;
            }
#pragma unroll
        for (int r = 0; r < 4; ++r) {
            A1[r] = rsum16(A1[r]);
            A2[r] = rsum16(A2[r]);
            A3[r] = rsum16(A3[r]);
            A4[r] = rsum16(A4[r]);
            A5[r] = rsum16(A5[r]);
            A6[r] = rsum16(A6[r]);
        }
        float mu4[4], rstd4[4], m1[4], m2[4], rl[4];
#pragma unroll
        for (int r = 0; r < 4; ++r) {
            float mu = A1[r] * (1.f / 64.f);
            float var = A2[r] * (1.f / 64.f) - mu * mu;
            float rstd = rsqrtf(var + 1e-5f);
            float T1m = A3[r] * (1.f / 64.f);
            float T2m = A4[r] * (1.f / 64.f);
            float T3m = A5[r] * (1.f / 64.f);
            float C1m = A6[r] * (1.f / 64.f);
            m1[r] = rstd * (T1m - mu * G2m) + C1m;
            m2[r] = rstd * rstd * (T2m - 2.f * mu * T1m + mu * mu * G2m) + rstd * (T3m - mu * C1m);
            mu4[r] = mu;
            rstd4[r] = rstd;
            rl[r] = rstd * lr4[r];  // includes -gs15
        }
        // gS' = -gs15 * lr * grad  (C-layout, feeds W-MFMA directly)
        float gS[4][4];
#pragma unroll
        for (int tn = 0; tn < 4; ++tn)
#pragma unroll
            for (int r = 0; r < 4; ++r) {
                float zh = (z[tn][r] - mu4[r]) * rstd4[r];
                float dzh = fmaf(g2[tn], zh, c1[tn * 4 + r]);
                gS[tn][r] = fmaf(-m2[r], zh, dzh - m1[r]) * rl[r];
            }
        // in-register B-frags (G') and A-frags (XKT)
        bf16x4_t gsB[4], xk4[4];
#pragma unroll
        for (int tn = 0; tn < 4; ++tn) {
            gsB[tn] = mk4(cvtpk(gS[tn][0], gS[tn][1]), cvtpk(gS[tn][2], gS[tn][3]));
            xk4[tn] = mk4(pk2r(kraw[tn * 4 + 0], kraw[tn * 4 + 1]), pk2r(kraw[tn * 4 + 2], kraw[tn * 4 + 3]));
        }

        // W update: Wc += XKT @ G'  (G' pre-scaled by -gs15) — pure MFMA accumulate
#pragma unroll
        for (int tm = 0; tm < 4; ++tm)
#pragma unroll
            for (int tn = 0; tn < 4; ++tn)
                Wc[tm][tn] = MFMA16(xk4[tm], gsB[tn], Wc[tm][tn]);
        {
            unsigned* wb32 = (unsigned*)WbL;
#pragma unroll
            for (int tn = 0; tn < 4; ++tn)
#pragma unroll
                for (int tm = 0; tm < 4; ++tm) {
                    int a = (tn * 16 + col) * 36 + tm * 8 + quad * 2;
                    wb32[a] = cvtpk(Wc[tm][tn][0], Wc[tm][tn][1]);
                    wb32[a + 1] = cvtpk(Wc[tm][tn][2], Wc[tm][tn][3]);
                }
        }

        // Z_bar = XQW(+bb) + ratio * (Pu @ G')   [= XQW + bb - gs4*(Pu@G)]
#pragma unroll
        for (int tn = 0; tn < 4; ++tn) {
            f32x4_t pg = MFMA16(pa4, gsB[tn], zf);
#pragma unroll
            for (int r = 0; r < 4; ++r) z[tn][r] = fmaf(ratio4[r], pg[r], xqw[tn][r]);
        }
        // y = XQ + ln_fwd(Z_bar)  -> bf16 (permuted layout, uint2 store)
#pragma unroll
        for (int r = 0; r < 4; ++r) {
            float s1 = z[0][r] + z[1][r] + z[2][r] + z[3][r];
            float s2 = z[0][r] * z[0][r] + z[1][r] * z[1][r] + z[2][r] * z[2][r] + z[3][r] * z[3][r];
            s1 = rsum16(s1);
            s2 = rsum16(s2);
            float mu = s1 * (1.f / 64.f);
            float var = s2 * (1.f / 64.f) - mu * mu;
            mu4[r] = mu;
            rstd4[r] = rsqrtf(var + 1e-5f);
        }
#pragma unroll
        for (int r = 0; r < 4; ++r) {
            float y0 = b2f(qraw[0 * 4 + r]) + gd4[0] * (z[0][r] - mu4[r]) * rstd4[r] + bd4[0];
            float y1 = b2f(qraw[1 * 4 + r]) + gd4[1] * (z[1][r] - mu4[r]) * rstd4[r] + bd4[1];
            float y2 = b2f(qraw[2 * 4 + r]) + gd4[2] * (z[2][r] - mu4[r]) * rstd4[r] + bd4[2];
            float y3 = b2f(qraw[3 * 4 + r]) + gd4[3] * (z[3][r] - mu4[r]) * rstd4[r] + bd4[3];
            uint2 po;
            po.x = cvtpk(y0, y1);
            po.y = cvtpk(y2, y3);
            *(uint2*)(ys + (long)(b * SS + s0 + quad * 4 + r) * DD + h * 64 + col * 4) = po;
        }

        // b update: bb += colsum(G')   [= bb - gs15*colsum(G)]
#pragma unroll
        for (int tn = 0; tn < 4; ++tn) {
            float c = gS[tn][0] + gS[tn][1] + gS[tn][2] + gS[tn][3];
            c += __shfl_xor(c, 16);
            c += __shfl_xor(c, 32);
            bbv[tn] += c;
        }

        // hoisted: wbf(n+1) read (WbL writes above are in-wave ordered)
#pragma unroll
        for (int tn = 0; tn < 4; ++tn)
#pragma unroll
            for (int kh = 0; kh < 2; ++kh)
                wbf[tn][kh] = *(const bf16x8_t*)&WbL[(tn * 16 + col) * 72 + kh * 32 + quad * 8];

        ka[0] = nka[0]; ka[1] = nka[1];
        qa[0] = nqa[0]; qa[1] = nqa[1];
#pragma unroll
        for (int r = 0; r < 4; ++r) lr4[r] = nlr[r];
#pragma unroll
        for (int j = 0; j < 16; ++j) { kraw[j] = nkraw[j]; vraw[j] = nvraw[j]; qraw[j] = nqraw[j]; }
    }
}

// ---------------- post layernorm (bf16 in, PERMUTED space) -> bf16 out (permuted) ----------------
__global__ __launch_bounds__(256) void k_postln(const u16* __restrict__ ys, const float* __restrict__ pg,
                                                const float* __restrict__ pb, u16* __restrict__ outb) {
    __shared__ float red[8];
    int row = blockIdx.x, tid = threadIdx.x, lane = tid & 63, wv = tid >> 6;
    const u16* rp = ys + row * 2048 + tid * 8;
    uint4 pkd = *(const uint4*)rp;
    float v[8];
    v[0] = b2f((u16)pkd.x); v[1] = b2f((u16)(pkd.x >> 16));
    v[2] = b2f((u16)pkd.y); v[3] = b2f((u16)(pkd.y >> 16));
    v[4] = b2f((u16)pkd.z); v[5] = b2f((u16)(pkd.z >> 16));
    v[6] = b2f((u16)pkd.w); v[7] = b2f((u16)(pkd.w >> 16));
    float s1 = 0.f, s2 = 0.f;
#pragma unroll
    for (int i = 0; i < 8; ++i) { s1 += v[i]; s2 += v[i] * v[i]; }
    s1 = wsum(s1);
    s2 = wsum(s2);
    if (lane == 0) {
        red[wv] = s1;
        red[wv + 4] = s2;
    }
    __syncthreads();
    float S1 = red[0] + red[1] + red[2] + red[3];
    float S2 = red[4] + red[5] + red[6] + red[7];
    float mu = S1 * (1.f / 2048), var = S2 * (1.f / 2048) - mu * mu;
    float rstd = rsqrtf(var + 1e-5f);
    const float4 g0 = *(const float4*)(pg + tid * 8);
    const float4 g1 = *(const float4*)(pg + tid * 8 + 4);
    const float4 b0v = *(const float4*)(pb + tid * 8);
    const float4 b1v = *(const float4*)(pb + tid * 8 + 4);
    float o[8];
    o[0] = g0.x * (v[0] - mu) * rstd + b0v.x;
    o[1] = g0.y * (v[1] - mu) * rstd + b0v.y;
    o[2] = g0.z * (v[2] - mu) * rstd + b0v.z;
    o[3] = g0.w * (v[3] - mu) * rstd + b0v.w;
    o[4] = g1.x * (v[4] - mu) * rstd + b1v.x;
    o[5] = g1.y * (v[5] - mu) * rstd + b1v.y;
    o[6] = g1.z * (v[6] - mu) * rstd + b1v.z;
    o[7] = g1.w * (v[7] - mu) * rstd + b1v.w;
    uint4 po;
    po.x = pk2(o[0], o[1]);
    po.y = pk2(o[2], o[3]);
    po.z = pk2(o[4], o[5]);
    po.w = pk2(o[6], o[7]);
    *(uint4*)(outb + row * 2048 + tid * 8) = po;
}

extern "C" void kernel_launch(void* const* d_in, const int* in_sizes, int n_in,
                              void* d_out, int out_size, void* d_ws, size_t ws_size,
                              hipStream_t stream) {
    const float* x = (const float*)d_in[0];
    const float* pf = (const float*)d_in[1];
    const float* Wq = (const float*)d_in[2];
    const float* Wk = (const float*)d_in[3];
    const float* Wv = (const float*)d_in[4];
    const float* Wo = (const float*)d_in[5];
    const float* pg = (const float*)d_in[6];
    const float* pb = (const float*)d_in[7];
    const float* ilrW = (const float*)d_in[8];
    const float* ilrb = (const float*)d_in[9];
    const float* lgs = (const float*)d_in[10];
    const float* tg = (const float*)d_in[11];
    const float* tb = (const float*)d_in[12];
    const float* W0 = (const float*)d_in[13];
    const float* b0 = (const float*)d_in[14];
    float* out = (float*)d_out;
    char* ws = (char*)d_ws;

    // workspace layout
    u16* xbf = (u16*)(ws + 0);             // 16 MB  (reused as lnb later)
    u16* wqb = (u16*)(ws + 16777216);      // 8 MB
    u16* wkb = (u16*)(ws + 25165824);      // 8 MB
    u16* wvb = (u16*)(ws + 33554432);      // 8 MB
    u16* wob = (u16*)(ws + 41943040);      // 8 MB   (permuted k-columns)
    u16* qbuf = (u16*)(ws + 50331648);     // 16 MB  (std layout, RoPE'd)
    u16* kbuf = (u16*)(ws + 67108864);     // 16 MB  (std layout, RoPE'd)
    u16* vbuf = (u16*)(ws + 83886080);     // 16 MB  (PERMUTED layout, RoPE'd)
    float* ct = (float*)(ws + 100663296);  // 256 KB
    float* st = (float*)(ws + 100925440);  // 256 KB
    float* lrb = (float*)(ws + 101187584); // 512 KB
    u16* ysb = (u16*)(ws + 101711872);     // 16 MB (bf16, permuted space)
    float* pgp = (float*)(ws + 118489088); // 8 KB
    float* pbp = (float*)(ws + 118497280); // 8 KB
    u16* lnb = (u16*)(ws + 0);             // reuse xbf region (dead after QKV GEMMs + k_lr)

    k_cvt5<<<dim3(4096, 6), 256, 0, stream>>>(x, Wq, Wk, Wv, Wo, xbf, wqb, wkb, wvb, wob);
    k_trig<<<256, 256, 0, stream>>>(pf, ct, st);
    k_ppg<<<8, 256, 0, stream>>>(pg, pb, pgp, pbp);

    k_gemm_bt<1><<<dim3(16, 32, 3), 256, 0, stream>>>(xbf, wqb, wkb, wvb, qbuf, kbuf, vbuf,
                                                      4096, 2048, 2048, ct, st);

    k_lr<<<1024, 256, 0, stream>>>(xbf, ilrW, ilrb, lrb);

    k_scan<<<64, 64, 0, stream>>>(qbuf, kbuf, vbuf, lrb, lgs, tg, tb, W0, b0, ysb);

    k_postln<<<4096, 256, 0, stream>>>(ysb, pgp, pbp, lnb);
    k_gemm_bt<0><<<dim3(16, 32, 1), 256, 0, stream>>>(lnb, wob, wob, wob, out, out, out,
                                                      4096, 2048, 2048, nullptr, nullptr);
}

// Round 8
// 706.926 us; speedup vs baseline: 1.0498x; 1.0498x over previous
//
#include <hip/hip_runtime.h>
#include <hip/hip_bf16.h>
#include <math.h>

// Problem constants
#define BB 2
#define SS 2048
#define DD 2048
#define HH 32
#define HDD 64
#define MBB 16
#define NN 128

typedef unsigned short u16;
typedef short bf16x8_t __attribute__((ext_vector_type(8)));
typedef short bf16x4_t __attribute__((ext_vector_type(4)));
typedef float f32x4_t __attribute__((ext_vector_type(4)));

__device__ __forceinline__ float b2f(u16 u) { return __uint_as_float(((unsigned)u) << 16); }
__device__ __forceinline__ u16 f2b(float f) {
    unsigned u = __float_as_uint(f);
    return (u16)((u + 0x7FFFu + ((u >> 16) & 1u)) >> 16);
}
__device__ __forceinline__ unsigned pk2(float a, float b) {
    return (unsigned)f2b(a) | ((unsigned)f2b(b) << 16);
}
// HW packed f32->bf16 (RNE, same rounding as f2b)
__device__ __forceinline__ unsigned cvtpk(float lo, float hi) {
    unsigned r;
    asm("v_cvt_pk_bf16_f32 %0, %1, %2" : "=v"(r) : "v"(lo), "v"(hi));
    return r;
}
__device__ __forceinline__ unsigned pk2r(u16 a, u16 b) { return (unsigned)a | ((unsigned)b << 16); }
__device__ __forceinline__ bf16x4_t mk4(unsigned lo, unsigned hi) {
    union { unsigned u[2]; bf16x4_t v; } t;
    t.u[0] = lo;
    t.u[1] = hi;
    return t.v;
}
// K=16 bf16 MFMA (gfx90a+ "1k" builtin). A/B frag: [row=lane&15][k=quad*4+j]
#define MFMA16(A, B, C) __builtin_amdgcn_mfma_f32_16x16x16bf16_1k((A), (B), (C), 0, 0, 0)

__device__ __forceinline__ float wsum(float x) {
    x += __shfl_xor(x, 32);
    x += __shfl_xor(x, 16);
    x += __shfl_xor(x, 8);
    x += __shfl_xor(x, 4);
    x += __shfl_xor(x, 2);
    x += __shfl_xor(x, 1);
    return x;
}

// DPP-based 16-lane row reduction (pure VALU, bit-identical to xor1/2/4/8 tree)
template <int CTRL>
__device__ __forceinline__ float dppadd(float x) {
    int t = __builtin_amdgcn_update_dpp(0, __float_as_int(x), CTRL, 0xF, 0xF, true);
    return x + __int_as_float(t);
}
__device__ __forceinline__ float rsum16(float x) {
    x = dppadd<0xB1>(x);   // quad_perm [1,0,3,2]  = xor1
    x = dppadd<0x4E>(x);   // quad_perm [2,3,0,1]  = xor2
    x = dppadd<0x141>(x);  // row_half_mirror
    x = dppadd<0x140>(x);  // row_mirror
    return x;
}

typedef __attribute__((address_space(3))) unsigned int lds_u32;
typedef __attribute__((address_space(1))) const unsigned int glb_u32;
__device__ __forceinline__ void async_copy16(const void* g, void* l) {
    __builtin_amdgcn_global_load_lds((glb_u32*)g, (lds_u32*)l, 16, 0, 0);
}

// within-head permutation: perm(d) = (d&15)*4 + (d>>4);  inverse: d = (j>>2) + (j&3)*16

// ---------------- fused fp32 -> bf16 for x + 4 weight matrices ----------------
__global__ __launch_bounds__(256) void k_cvt5(const float* __restrict__ x, const float* __restrict__ wq,
                                              const float* __restrict__ wk, const float* __restrict__ wv,
                                              const float* __restrict__ wo, u16* __restrict__ xb,
                                              u16* __restrict__ wqb, u16* __restrict__ wkb,
                                              u16* __restrict__ wvb, u16* __restrict__ wob) {
    int sl = blockIdx.y;
    long e = (long)(blockIdx.x * 256 + threadIdx.x) * 4;
    if (sl == 5) {
        long n = e >> 11;
        int cin = (int)(e & 2047);
        int hd0 = (cin >> 6) * 64 + ((cin & 63) >> 2);
        const float* src = wo + n * 2048 + hd0;
        float f0 = src[0], f1 = src[16], f2 = src[32], f3 = src[48];
        uint2 o;
        o.x = pk2(f0, f1);
        o.y = pk2(f2, f3);
        *(uint2*)(wob + e) = o;
        return;
    }
    const float* s;
    u16* d;
    if (sl == 0) { s = x; d = xb; }
    else if (sl == 1) { s = x + 4194304; d = xb + 4194304; }
    else if (sl == 2) { s = wq; d = wqb; }
    else if (sl == 3) { s = wk; d = wkb; }
    else { s = wv; d = wvb; }
    float4 f = *(const float4*)(s + e);
    uint2 o;
    o.x = pk2(f.x, f.y);
    o.y = pk2(f.z, f.w);
    *(uint2*)(d + e) = o;
}

// ---------------- cos/sin tables ----------------
__global__ void k_trig(const float* __restrict__ pf, float* __restrict__ ct, float* __restrict__ st) {
    int i = blockIdx.x * 256 + threadIdx.x;  // 65536 = S*32
    float f = pf[i];
    ct[i] = cosf(f);
    st[i] = sinf(f);
}

// ---------------- permuted post-LN gamma/beta ----------------
__global__ void k_ppg(const float* __restrict__ pg, const float* __restrict__ pb,
                      float* __restrict__ pgp, float* __restrict__ pbp) {
    int i = blockIdx.x * 256 + threadIdx.x;  // 2048
    int h = i >> 6, o = i & 63;
    int src = h * 64 + (o >> 2) + (o & 3) * 16;
    pgp[i] = pg[src];
    pbp[i] = pb[src];
}

// ---------------- bf16 MFMA GEMM:  C[M,N] = A[M,K] * B[N,K]^T ----------------
// EPI 0: store fp32 row-major. EPI 1: RoPE + bf16 (B,H,S,HD):
//   z==2 (V): store PERMUTED only; z==0/1 (Q/K): store std AND permuted copy (P0/P1)
//   so the scan's C-layout gathers become ushort4 loads with no extra kernel.
template <int EPI>
__global__ __launch_bounds__(256) void k_gemm_bt(const u16* __restrict__ A, const u16* __restrict__ B0,
                                                 const u16* __restrict__ B1, const u16* __restrict__ B2,
                                                 void* __restrict__ C0, void* __restrict__ C1,
                                                 void* __restrict__ C2, int M, int Nn, int K,
                                                 const float* __restrict__ ct, const float* __restrict__ st,
                                                 u16* __restrict__ P0, u16* __restrict__ P1) {
    __shared__ u16 As[128 * 32];
    __shared__ u16 Bs[128 * 32];
    int z = blockIdx.z;
    const u16* Bm = (z == 0) ? B0 : (z == 1) ? B1 : B2;
    void* Cout = (z == 0) ? C0 : (z == 1) ? C1 : C2;
    u16* Pout = (z == 0) ? P0 : P1;
    int tid = threadIdx.x, lane = tid & 63, wv = tid >> 6;
    int m0 = blockIdx.y * 128, n0 = blockIdx.x * 128;
    int wm = wv >> 1, wn = wv & 1;

    f32x4_t acc[4][4];
    f32x4_t zero = {0.f, 0.f, 0.f, 0.f};
#pragma unroll
    for (int a = 0; a < 4; ++a)
#pragma unroll
        for (int b = 0; b < 4; ++b) acc[a][b] = zero;

    int mrow = lane & 15, qk = (lane >> 4) * 8;
    const int kTiles = K >> 5;
    for (int kt = 0; kt < kTiles; ++kt) {
        __syncthreads();
        int kb = kt << 5;
#pragma unroll
        for (int it = 0; it < 2; ++it) {
            int cb = it * 256 + wv * 64;  // wave-uniform chunk base
            int c = cb + lane;
            const u16* gpA = A + (m0 + (c >> 2)) * K + kb + ((c & 3) << 3);
            async_copy16(gpA, &As[cb << 3]);
            const u16* gpB = Bm + (n0 + (c >> 2)) * K + kb + ((c & 3) << 3);
            async_copy16(gpB, &Bs[cb << 3]);
        }
        asm volatile("s_waitcnt vmcnt(0)" ::: "memory");
        __syncthreads();

        bf16x8_t af[4], bfr[4];
#pragma unroll
        for (int mi = 0; mi < 4; ++mi)
            af[mi] = *(const bf16x8_t*)&As[(wm * 64 + mi * 16 + mrow) * 32 + qk];
#pragma unroll
        for (int ni = 0; ni < 4; ++ni)
            bfr[ni] = *(const bf16x8_t*)&Bs[(wn * 64 + ni * 16 + mrow) * 32 + qk];
#pragma unroll
        for (int mi = 0; mi < 4; ++mi)
#pragma unroll
            for (int ni = 0; ni < 4; ++ni)
                acc[mi][ni] = __builtin_amdgcn_mfma_f32_16x16x32_bf16(af[mi], bfr[ni], acc[mi][ni], 0, 0, 0);
    }

    int col16 = lane & 15, rq = (lane >> 4) * 4;
#pragma unroll
    for (int mi = 0; mi < 4; ++mi) {
#pragma unroll
        for (int ni = 0; ni < 4; ++ni) {
#pragma unroll
            for (int r = 0; r < 4; ++r) {
                int gr = m0 + wm * 64 + mi * 16 + rq + r;
                int gc = n0 + wn * 64 + ni * 16 + col16;
                float val = acc[mi][ni][r];
                if (EPI == 0) {
                    ((float*)Cout)[gr * Nn + gc] = val;
                } else {
                    // fused RoPE: pair partner sits on lane^1 (gc differs in bit 0)
                    int b = gr >> 11, s2 = gr & 2047, hh = gc >> 6, hd = gc & 63;
                    int fi = s2 * 32 + (hd >> 1);
                    float c = ct[fi], sn = st[fi];
                    float partner = __shfl_xor(val, 1);
                    float y = (gc & 1) ? (partner * sn + val * c) : (val * c - partner * sn);
                    u16 yb = f2b(y);
                    long rowb = (((long)(b * HH + hh) * SS) + s2) * HDD;
                    int po = (hd & 15) * 4 + (hd >> 4);
                    if (z == 2) {
                        ((u16*)Cout)[rowb + po] = yb;  // V: permuted only
                    } else {
                        ((u16*)Cout)[rowb + hd] = yb;  // std (A-frags)
                        Pout[rowb + po] = yb;          // permuted (C-layout raws)
                    }
                }
            }
        }
    }
}

// ---------------- ilr gate ----------------
__global__ __launch_bounds__(256) void k_lr(const u16* __restrict__ xb, const float* __restrict__ ilrW,
                                            const float* __restrict__ ilrb, float* __restrict__ lrout) {
    __shared__ u16 xr[4][2048];
    int row0 = blockIdx.x * 4;
    int tid = threadIdx.x, lane = tid & 63, wv = tid >> 6;
    const unsigned* src = (const unsigned*)(xb + row0 * 2048);
    unsigned* dst = (unsigned*)xr;
    for (int i = tid; i < 4096; i += 256) dst[i] = src[i];
    __syncthreads();
    int b = row0 >> 11, s0 = row0 & 2047;
#pragma unroll
    for (int sub = 0; sub < 8; ++sub) {
        int h = wv * 8 + sub;
        const float* wp = ilrW + h * 2048;
        float a0 = 0.f, a1 = 0.f, a2 = 0.f, a3 = 0.f;
        for (int i = 0; i < 16; ++i) {
            int idx = i * 128 + lane * 2;
            float2 w2 = *(const float2*)(wp + idx);
            unsigned p0 = *(const unsigned*)&xr[0][idx];
            unsigned p1 = *(const unsigned*)&xr[1][idx];
            unsigned p2 = *(const unsigned*)&xr[2][idx];
            unsigned p3 = *(const unsigned*)&xr[3][idx];
            a0 += b2f((u16)p0) * w2.x + b2f((u16)(p0 >> 16)) * w2.y;
            a1 += b2f((u16)p1) * w2.x + b2f((u16)(p1 >> 16)) * w2.y;
            a2 += b2f((u16)p2) * w2.x + b2f((u16)(p2 >> 16)) * w2.y;
            a3 += b2f((u16)p3) * w2.x + b2f((u16)(p3 >> 16)) * w2.y;
        }
        a0 = wsum(a0);
        a1 = wsum(a1);
        a2 = wsum(a2);
        a3 = wsum(a3);
        if (lane == 0) {
            float bv = ilrb[h];
            float* op = lrout + ((b * HH + h) * SS) + s0;
            op[0] = (1.0f / (1.0f + expf(-(a0 + bv)))) * (1.0f / 64.0f);
            op[1] = (1.0f / (1.0f + expf(-(a1 + bv)))) * (1.0f / 64.0f);
            op[2] = (1.0f / (1.0f + expf(-(a2 + bv)))) * (1.0f / 64.0f);
            op[3] = (1.0f / (1.0f + expf(-(a3 + bv)))) * (1.0f / 64.0f);
        }
    }
}

// ---------------- TTT scan: ONE WAVE per (b,h) ----------------
// Round-8: per-step global loads cut 44 -> 20, all wide (the C-layout kraw/qraw
// gathers now read permuted copies qpc/kpc as ushort4 — bit-identical values),
// and the prefetch block moved to the TOP of the step so all loads issue before
// the wbf lgkmcnt wait (full step of slack; targets suspected load-clump stalls).
__global__ __launch_bounds__(64, 1) void k_scan(const u16* __restrict__ qb, const u16* __restrict__ kb2,
                                                const u16* __restrict__ qpc, const u16* __restrict__ kpc,
                                                const u16* __restrict__ vc, const float* __restrict__ lrbuf,
                                                const float* __restrict__ lgs, const float* __restrict__ tg,
                                                const float* __restrict__ tb, const float* __restrict__ W0,
                                                const float* __restrict__ b0, u16* __restrict__ ys) {
    __shared__ u16 WbL[64 * 72];  // [d2][d1] bf16 W for next step's B-frags

    const int bh = blockIdx.x, h = bh & 31, b = bh >> 5;
    const int lane = threadIdx.x & 63;
    const int quad = lane >> 4, col = lane & 15;
    const int base = bh * SS;

    float gd4[4], bd4[4], bbv[4], g2[4], gb[4];
#pragma unroll
    for (int tn = 0; tn < 4; ++tn) {
        gd4[tn] = tg[h * 64 + tn * 16 + col];
        bd4[tn] = tb[h * 64 + tn * 16 + col];
        bbv[tn] = b0[h * 64 + tn * 16 + col];
        g2[tn] = gd4[tn] * gd4[tn];
        gb[tn] = gd4[tn] * bd4[tn];
    }
    float G2m;  // mean over d of gamma^2
    {
        float s = g2[0] + g2[1] + g2[2] + g2[3];
        s = rsum16(s);
        G2m = s * (1.f / 64.f);
    }
    const float gs15 = fmaxf(1.f / 16.f + lgs[15], 0.f);
    const float inv15 = gs15 > 0.f ? 1.f / gs15 : 0.f;
    float gs4[4], ratio4[4];
#pragma unroll
    for (int r = 0; r < 4; ++r) {
        int i = quad * 4 + r;
        gs4[r] = fmaxf(1.f / (float)(i + 1) + lgs[i], 0.f);
        ratio4[r] = gs4[r] * inv15;
    }

    f32x4_t Wc[4][4];
#pragma unroll
    for (int tm = 0; tm < 4; ++tm)
#pragma unroll
        for (int tn = 0; tn < 4; ++tn)
#pragma unroll
            for (int r = 0; r < 4; ++r)
                Wc[tm][tn][r] = W0[h * 4096 + (tm * 16 + quad * 4 + r) * 64 + tn * 16 + col];

    {  // initial Wb
        unsigned* wb32 = (unsigned*)WbL;
#pragma unroll
        for (int tn = 0; tn < 4; ++tn)
#pragma unroll
            for (int tm = 0; tm < 4; ++tm) {
                int a = (tn * 16 + col) * 36 + tm * 8 + quad * 2;  // u32 units; row stride 36 u32
                wb32[a] = cvtpk(Wc[tm][tn][0], Wc[tm][tn][1]);
                wb32[a + 1] = cvtpk(Wc[tm][tn][2], Wc[tm][tn][3]);
            }
    }

    // prefetch chunk 0 (lr pre-scaled by -gs15)
    bf16x8_t ka[2], qa[2];
    float lr4[4];
    u16 kraw[16], vraw[16], qraw[16];
    {
        const u16* kp = kb2 + (base + col) * 64;
        const u16* qp = qb + (base + col) * 64;
#pragma unroll
        for (int kh = 0; kh < 2; ++kh) {
            ka[kh] = *(const bf16x8_t*)(kp + kh * 32 + quad * 8);
            qa[kh] = *(const bf16x8_t*)(qp + kh * 32 + quad * 8);
        }
#pragma unroll
        for (int r = 0; r < 4; ++r) lr4[r] = -gs15 * lrbuf[base + quad * 4 + r];
#pragma unroll
        for (int r = 0; r < 4; ++r) {
            long ro = (long)(base + quad * 4 + r) * 64 + col * 4;
            ushort4 tk = *(const ushort4*)(kpc + ro);
            ushort4 tv = *(const ushort4*)(vc + ro);
            ushort4 tq = *(const ushort4*)(qpc + ro);
            kraw[r] = tk.x; kraw[4 + r] = tk.y; kraw[8 + r] = tk.z; kraw[12 + r] = tk.w;
            vraw[r] = tv.x; vraw[4 + r] = tv.y; vraw[8 + r] = tv.z; vraw[12 + r] = tv.w;
            qraw[r] = tq.x; qraw[4 + r] = tq.y; qraw[8 + r] = tq.z; qraw[12 + r] = tq.w;
        }
    }

    // prologue: wbf(0) read
    bf16x8_t wbf[4][2];
#pragma unroll
    for (int tn = 0; tn < 4; ++tn)
#pragma unroll
        for (int kh = 0; kh < 2; ++kh)
            wbf[tn][kh] = *(const bf16x8_t*)&WbL[(tn * 16 + col) * 72 + kh * 32 + quad * 8];

    const f32x4_t zf = {0.f, 0.f, 0.f, 0.f};

    for (int n = 0; n < NN; ++n) {
        const int s0 = n * 16;

        // prefetch next chunk FIRST (loads issue before the wbf lgkm wait; full-step slack)
        bf16x8_t nka[2], nqa[2];
        float nlr[4];
        u16 nkraw[16], nvraw[16], nqraw[16];
        {
            const int sp = (n + 1 < NN) ? s0 + 16 : s0;
            const u16* kp = kb2 + (base + sp + col) * 64;
            const u16* qp = qb + (base + sp + col) * 64;
#pragma unroll
            for (int kh = 0; kh < 2; ++kh) {
                nka[kh] = *(const bf16x8_t*)(kp + kh * 32 + quad * 8);
                nqa[kh] = *(const bf16x8_t*)(qp + kh * 32 + quad * 8);
            }
#pragma unroll
            for (int r = 0; r < 4; ++r) nlr[r] = -gs15 * lrbuf[base + sp + quad * 4 + r];
#pragma unroll
            for (int r = 0; r < 4; ++r) {
                long ro = (long)(base + sp + quad * 4 + r) * 64 + col * 4;
                ushort4 tk = *(const ushort4*)(kpc + ro);
                ushort4 tv = *(const ushort4*)(vc + ro);
                ushort4 tq = *(const ushort4*)(qpc + ro);
                nkraw[r] = tk.x; nkraw[4 + r] = tk.y; nkraw[8 + r] = tk.z; nkraw[12 + r] = tk.w;
                nvraw[r] = tv.x; nvraw[4 + r] = tv.y; nvraw[8 + r] = tv.z; nvraw[12 + r] = tv.w;
                nqraw[r] = tq.x; nqraw[4 + r] = tq.y; nqraw[8 + r] = tq.z; nqraw[12 + r] = tq.w;
            }
        }

        // Z = XK@W + bb, XQW = XQ@W + bb (bb as MFMA C-init), AttnT = XK@XQ^T
        f32x4_t z[4], xqw[4], attnT;
#pragma unroll
        for (int tn = 0; tn < 4; ++tn) {
            f32x4_t cb = {bbv[tn], bbv[tn], bbv[tn], bbv[tn]};
            z[tn] = __builtin_amdgcn_mfma_f32_16x16x32_bf16(ka[1], wbf[tn][1], cb, 0, 0, 0);
            z[tn] = __builtin_amdgcn_mfma_f32_16x16x32_bf16(ka[0], wbf[tn][0], z[tn], 0, 0, 0);
            xqw[tn] = __builtin_amdgcn_mfma_f32_16x16x32_bf16(qa[1], wbf[tn][1], cb, 0, 0, 0);
            xqw[tn] = __builtin_amdgcn_mfma_f32_16x16x32_bf16(qa[0], wbf[tn][0], xqw[tn], 0, 0, 0);
        }
        attnT = __builtin_amdgcn_mfma_f32_16x16x32_bf16(ka[1], qa[1], zf, 0, 0, 0);
        attnT = __builtin_amdgcn_mfma_f32_16x16x32_bf16(ka[0], qa[0], attnT, 0, 0, 0);

        // lane holds Attn[i=col][j=quad*4+r]; tril mask j<=i, in-register Pu A-frag
        float pv0 = (quad * 4 + 0 <= col) ? (1.f + attnT[0]) : 0.f;
        float pv1 = (quad * 4 + 1 <= col) ? (1.f + attnT[1]) : 0.f;
        float pv2 = (quad * 4 + 2 <= col) ? (1.f + attnT[2]) : 0.f;
        float pv3 = (quad * 4 + 3 <= col) ? (1.f + attnT[3]) : 0.f;
        bf16x4_t pa4 = mk4(cvtpk(pv0, pv1), cvtpk(pv2, pv3));

        // fused ln_l2_bwd: single DPP reduce phase over 6 sums (z already includes bb)
        float c1[16];
        float A1[4], A2[4], A3[4], A4[4], A5[4], A6[4];
#pragma unroll
        for (int r = 0; r < 4; ++r) { A1[r] = 0.f; A2[r] = 0.f; A3[r] = 0.f; A4[r] = 0.f; A5[r] = 0.f; A6[r] = 0.f; }
#pragma unroll
        for (int tn = 0; tn < 4; ++tn)
#pragma unroll
            for (int r = 0; r < 4; ++r) {
                float zv = z[tn][r];
                float tgt = b2f(vraw[tn * 4 + r]) - b2f(kraw[tn * 4 + r]);
                float c = gb[tn] - gd4[tn] * tgt;  // g*(b - tgt)
                c1[tn * 4 + r] = c;
                float t = g2[tn] * zv;
                A1[r] += zv;
                A2[r] = fmaf(zv, zv, A2[r]);
                A3[r] += t;
                A4[r] = fmaf(t, zv, A4[r]);
                A5[r] = fmaf(c, zv, A5[r]);
                A6[r] += c;
            }
#pragma unroll
        for (int r = 0; r < 4; ++r) {
            A1[r] = rsum16(A1[r]);
            A2[r] = rsum16(A2[r]);
            A3[r] = rsum16(A3[r]);
            A4[r] = rsum16(A4[r]);
            A5[r] = rsum16(A5[r]);
            A6[r] = rsum16(A6[r]);
        }
        float mu4[4], rstd4[4], m1[4], m2[4], rl[4];
#pragma unroll
        for (int r = 0; r < 4; ++r) {
            float mu = A1[r] * (1.f / 64.f);
            float var = A2[r] * (1.f / 64.f) - mu * mu;
            float rstd = rsqrtf(var + 1e-5f);
            float T1m = A3[r] * (1.f / 64.f);
            float T2m = A4[r] * (1.f / 64.f);
            float T3m = A5[r] * (1.f / 64.f);
            float C1m = A6[r] * (1.f / 64.f);
            m1[r] = rstd * (T1m - mu * G2m) + C1m;
            m2[r] = rstd * rstd * (T2m - 2.f * mu * T1m + mu * mu * G2m) + rstd * (T3m - mu * C1m);
            mu4[r] = mu;
            rstd4[r] = rstd;
            rl[r] = rstd * lr4[r];  // includes -gs15
        }
        // gS' = -gs15 * lr * grad  (C-layout, feeds W-MFMA directly)
        float gS[4][4];
#pragma unroll
        for (int tn = 0; tn < 4; ++tn)
#pragma unroll
            for (int r = 0; r < 4; ++r) {
                float zh = (z[tn][r] - mu4[r]) * rstd4[r];
                float dzh = fmaf(g2[tn], zh, c1[tn * 4 + r]);
                gS[tn][r] = fmaf(-m2[r], zh, dzh - m1[r]) * rl[r];
            }
        // in-register B-frags (G') and A-frags (XKT)
        bf16x4_t gsB[4], xk4[4];
#pragma unroll
        for (int tn = 0; tn < 4; ++tn) {
            gsB[tn] = mk4(cvtpk(gS[tn][0], gS[tn][1]), cvtpk(gS[tn][2], gS[tn][3]));
            xk4[tn] = mk4(pk2r(kraw[tn * 4 + 0], kraw[tn * 4 + 1]), pk2r(kraw[tn * 4 + 2], kraw[tn * 4 + 3]));
        }

        // W update: Wc += XKT @ G'  (G' pre-scaled by -gs15) — pure MFMA accumulate
#pragma unroll
        for (int tm = 0; tm < 4; ++tm)
#pragma unroll
            for (int tn = 0; tn < 4; ++tn)
                Wc[tm][tn] = MFMA16(xk4[tm], gsB[tn], Wc[tm][tn]);
        {
            unsigned* wb32 = (unsigned*)WbL;
#pragma unroll
            for (int tn = 0; tn < 4; ++tn)
#pragma unroll
                for (int tm = 0; tm < 4; ++tm) {
                    int a = (tn * 16 + col) * 36 + tm * 8 + quad * 2;
                    wb32[a] = cvtpk(Wc[tm][tn][0], Wc[tm][tn][1]);
                    wb32[a + 1] = cvtpk(Wc[tm][tn][2], Wc[tm][tn][3]);
                }
        }

        // Z_bar = XQW(+bb) + ratio * (Pu @ G')   [= XQW + bb - gs4*(Pu@G)]
#pragma unroll
        for (int tn = 0; tn < 4; ++tn) {
            f32x4_t pg = MFMA16(pa4, gsB[tn], zf);
#pragma unroll
            for (int r = 0; r < 4; ++r) z[tn][r] = fmaf(ratio4[r], pg[r], xqw[tn][r]);
        }
        // y = XQ + ln_fwd(Z_bar)  -> bf16 (permuted layout, uint2 store)
#pragma unroll
        for (int r = 0; r < 4; ++r) {
            float s1 = z[0][r] + z[1][r] + z[2][r] + z[3][r];
            float s2 = z[0][r] * z[0][r] + z[1][r] * z[1][r] + z[2][r] * z[2][r] + z[3][r] * z[3][r];
            s1 = rsum16(s1);
            s2 = rsum16(s2);
            float mu = s1 * (1.f / 64.f);
            float var = s2 * (1.f / 64.f) - mu * mu;
            mu4[r] = mu;
            rstd4[r] = rsqrtf(var + 1e-5f);
        }
#pragma unroll
        for (int r = 0; r < 4; ++r) {
            float y0 = b2f(qraw[0 * 4 + r]) + gd4[0] * (z[0][r] - mu4[r]) * rstd4[r] + bd4[0];
            float y1 = b2f(qraw[1 * 4 + r]) + gd4[1] * (z[1][r] - mu4[r]) * rstd4[r] + bd4[1];
            float y2 = b2f(qraw[2 * 4 + r]) + gd4[2] * (z[2][r] - mu4[r]) * rstd4[r] + bd4[2];
            float y3 = b2f(qraw[3 * 4 + r]) + gd4[3] * (z[3][r] - mu4[r]) * rstd4[r] + bd4[3];
            uint2 po;
            po.x = cvtpk(y0, y1);
            po.y = cvtpk(y2, y3);
            *(uint2*)(ys + (long)(b * SS + s0 + quad * 4 + r) * DD + h * 64 + col * 4) = po;
        }

        // b update: bb += colsum(G')   [= bb - gs15*colsum(G)]
#pragma unroll
        for (int tn = 0; tn < 4; ++tn) {
            float c = gS[tn][0] + gS[tn][1] + gS[tn][2] + gS[tn][3];
            c += __shfl_xor(c, 16);
            c += __shfl_xor(c, 32);
            bbv[tn] += c;
        }

        // hoisted: wbf(n+1) read (WbL writes above are in-wave ordered)
#pragma unroll
        for (int tn = 0; tn < 4; ++tn)
#pragma unroll
            for (int kh = 0; kh < 2; ++kh)
                wbf[tn][kh] = *(const bf16x8_t*)&WbL[(tn * 16 + col) * 72 + kh * 32 + quad * 8];

        ka[0] = nka[0]; ka[1] = nka[1];
        qa[0] = nqa[0]; qa[1] = nqa[1];
#pragma unroll
        for (int r = 0; r < 4; ++r) lr4[r] = nlr[r];
#pragma unroll
        for (int j = 0; j < 16; ++j) { kraw[j] = nkraw[j]; vraw[j] = nvraw[j]; qraw[j] = nqraw[j]; }
    }
}

// ---------------- post layernorm (bf16 in, PERMUTED space) -> bf16 out (permuted) ----------------
__global__ __launch_bounds__(256) void k_postln(const u16* __restrict__ ys, const float* __restrict__ pg,
                                                const float* __restrict__ pb, u16* __restrict__ outb) {
    __shared__ float red[8];
    int row = blockIdx.x, tid = threadIdx.x, lane = tid & 63, wv = tid >> 6;
    const u16* rp = ys + row * 2048 + tid * 8;
    uint4 pkd = *(const uint4*)rp;
    float v[8];
    v[0] = b2f((u16)pkd.x); v[1] = b2f((u16)(pkd.x >> 16));
    v[2] = b2f((u16)pkd.y); v[3] = b2f((u16)(pkd.y >> 16));
    v[4] = b2f((u16)pkd.z); v[5] = b2f((u16)(pkd.z >> 16));
    v[6] = b2f((u16)pkd.w); v[7] = b2f((u16)(pkd.w >> 16));
    float s1 = 0.f, s2 = 0.f;
#pragma unroll
    for (int i = 0; i < 8; ++i) { s1 += v[i]; s2 += v[i] * v[i]; }
    s1 = wsum(s1);
    s2 = wsum(s2);
    if (lane == 0) {
        red[wv] = s1;
        red[wv + 4] = s2;
    }
    __syncthreads();
    float S1 = red[0] + red[1] + red[2] + red[3];
    float S2 = red[4] + red[5] + red[6] + red[7];
    float mu = S1 * (1.f / 2048), var = S2 * (1.f / 2048) - mu * mu;
    float rstd = rsqrtf(var + 1e-5f);
    const float4 g0 = *(const float4*)(pg + tid * 8);
    const float4 g1 = *(const float4*)(pg + tid * 8 + 4);
    const float4 b0v = *(const float4*)(pb + tid * 8);
    const float4 b1v = *(const float4*)(pb + tid * 8 + 4);
    float o[8];
    o[0] = g0.x * (v[0] - mu) * rstd + b0v.x;
    o[1] = g0.y * (v[1] - mu) * rstd + b0v.y;
    o[2] = g0.z * (v[2] - mu) * rstd + b0v.z;
    o[3] = g0.w * (v[3] - mu) * rstd + b0v.w;
    o[4] = g1.x * (v[4] - mu) * rstd + b1v.x;
    o[5] = g1.y * (v[5] - mu) * rstd + b1v.y;
    o[6] = g1.z * (v[6] - mu) * rstd + b1v.z;
    o[7] = g1.w * (v[7] - mu) * rstd + b1v.w;
    uint4 po;
    po.x = pk2(o[0], o[1]);
    po.y = pk2(o[2], o[3]);
    po.z = pk2(o[4], o[5]);
    po.w = pk2(o[6], o[7]);
    *(uint4*)(outb + row * 2048 + tid * 8) = po;
}

extern "C" void kernel_launch(void* const* d_in, const int* in_sizes, int n_in,
                              void* d_out, int out_size, void* d_ws, size_t ws_size,
                              hipStream_t stream) {
    const float* x = (const float*)d_in[0];
    const float* pf = (const float*)d_in[1];
    const float* Wq = (const float*)d_in[2];
    const float* Wk = (const float*)d_in[3];
    const float* Wv = (const float*)d_in[4];
    const float* Wo = (const float*)d_in[5];
    const float* pg = (const float*)d_in[6];
    const float* pb = (const float*)d_in[7];
    const float* ilrW = (const float*)d_in[8];
    const float* ilrb = (const float*)d_in[9];
    const float* lgs = (const float*)d_in[10];
    const float* tg = (const float*)d_in[11];
    const float* tb = (const float*)d_in[12];
    const float* W0 = (const float*)d_in[13];
    const float* b0 = (const float*)d_in[14];
    float* out = (float*)d_out;
    char* ws = (char*)d_ws;

    // workspace layout
    u16* xbf = (u16*)(ws + 0);             // 16 MB  (reused as lnb later)
    u16* wqb = (u16*)(ws + 16777216);      // 8 MB
    u16* wkb = (u16*)(ws + 25165824);      // 8 MB
    u16* wvb = (u16*)(ws + 33554432);      // 8 MB
    u16* wob = (u16*)(ws + 41943040);      // 8 MB   (permuted k-columns)
    u16* qbuf = (u16*)(ws + 50331648);     // 16 MB  (std layout, RoPE'd)
    u16* kbuf = (u16*)(ws + 67108864);     // 16 MB  (std layout, RoPE'd)
    u16* vbuf = (u16*)(ws + 83886080);     // 16 MB  (PERMUTED layout, RoPE'd)
    float* ct = (float*)(ws + 100663296);  // 256 KB
    float* st = (float*)(ws + 100925440);  // 256 KB
    float* lrb = (float*)(ws + 101187584); // 512 KB
    u16* ysb = (u16*)(ws + 101711872);     // 16 MB (bf16, permuted space)
    float* pgp = (float*)(ws + 118489088); // 8 KB
    float* pbp = (float*)(ws + 118497280); // 8 KB
    u16* qpc = (u16*)(ws + 118505472);     // 16 MB (permuted q copy)
    u16* kpc = (u16*)(ws + 135282688);     // 16 MB (permuted k copy) -> end ~152 MB
    u16* lnb = (u16*)(ws + 0);             // reuse xbf region (dead after QKV GEMMs + k_lr)

    k_cvt5<<<dim3(4096, 6), 256, 0, stream>>>(x, Wq, Wk, Wv, Wo, xbf, wqb, wkb, wvb, wob);
    k_trig<<<256, 256, 0, stream>>>(pf, ct, st);
    k_ppg<<<8, 256, 0, stream>>>(pg, pb, pgp, pbp);

    k_gemm_bt<1><<<dim3(16, 32, 3), 256, 0, stream>>>(xbf, wqb, wkb, wvb, qbuf, kbuf, vbuf,
                                                      4096, 2048, 2048, ct, st, qpc, kpc);

    k_lr<<<1024, 256, 0, stream>>>(xbf, ilrW, ilrb, lrb);

    k_scan<<<64, 64, 0, stream>>>(qbuf, kbuf, qpc, kpc, vbuf, lrb, lgs, tg, tb, W0, b0, ysb);

    k_postln<<<4096, 256, 0, stream>>>(ysb, pgp, pbp, lnb);
    k_gemm_bt<0><<<dim3(16, 32, 1), 256, 0, stream>>>(lnb, wob, wob, wob, out, out, out,
                                                      4096, 2048, 2048, nullptr, nullptr, nullptr, nullptr);
}

// Round 9
// 702.690 us; speedup vs baseline: 1.0561x; 1.0060x over previous
//
#include <hip/hip_runtime.h>
#include <hip/hip_bf16.h>
#include <math.h>

// Problem constants
#define BB 2
#define SS 2048
#define DD 2048
#define HH 32
#define HDD 64
#define MBB 16
#define NN 128

typedef unsigned short u16;
typedef short bf16x8_t __attribute__((ext_vector_type(8)));
typedef short bf16x4_t __attribute__((ext_vector_type(4)));
typedef float f32x4_t __attribute__((ext_vector_type(4)));

__device__ __forceinline__ float b2f(u16 u) { return __uint_as_float(((unsigned)u) << 16); }
__device__ __forceinline__ u16 f2b(float f) {
    unsigned u = __float_as_uint(f);
    return (u16)((u + 0x7FFFu + ((u >> 16) & 1u)) >> 16);
}
__device__ __forceinline__ unsigned pk2(float a, float b) {
    return (unsigned)f2b(a) | ((unsigned)f2b(b) << 16);
}
// HW packed f32->bf16 (RNE, same rounding as f2b)
__device__ __forceinline__ unsigned cvtpk(float lo, float hi) {
    unsigned r;
    asm("v_cvt_pk_bf16_f32 %0, %1, %2" : "=v"(r) : "v"(lo), "v"(hi));
    return r;
}
__device__ __forceinline__ unsigned pk2r(u16 a, u16 b) { return (unsigned)a | ((unsigned)b << 16); }
__device__ __forceinline__ bf16x4_t mk4(unsigned lo, unsigned hi) {
    union { unsigned u[2]; bf16x4_t v; } t;
    t.u[0] = lo;
    t.u[1] = hi;
    return t.v;
}
// K=16 bf16 MFMA (gfx90a+ "1k" builtin). A/B frag: [row=lane&15][k=quad*4+j]
#define MFMA16(A, B, C) __builtin_amdgcn_mfma_f32_16x16x16bf16_1k((A), (B), (C), 0, 0, 0)
#define MF(A, B, C) __builtin_amdgcn_mfma_f32_16x16x32_bf16((A), (B), (C), 0, 0, 0)

__device__ __forceinline__ float wsum(float x) {
    x += __shfl_xor(x, 32);
    x += __shfl_xor(x, 16);
    x += __shfl_xor(x, 8);
    x += __shfl_xor(x, 4);
    x += __shfl_xor(x, 2);
    x += __shfl_xor(x, 1);
    return x;
}

// DPP-based 16-lane row reduction (pure VALU, bit-identical to xor1/2/4/8 tree)
template <int CTRL>
__device__ __forceinline__ float dppadd(float x) {
    int t = __builtin_amdgcn_update_dpp(0, __float_as_int(x), CTRL, 0xF, 0xF, true);
    return x + __int_as_float(t);
}
__device__ __forceinline__ float rsum16(float x) {
    x = dppadd<0xB1>(x);   // quad_perm [1,0,3,2]  = xor1
    x = dppadd<0x4E>(x);   // quad_perm [2,3,0,1]  = xor2
    x = dppadd<0x141>(x);  // row_half_mirror
    x = dppadd<0x140>(x);  // row_mirror
    return x;
}

typedef __attribute__((address_space(3))) unsigned int lds_u32;
typedef __attribute__((address_space(1))) const unsigned int glb_u32;
__device__ __forceinline__ void async_copy16(const void* g, void* l) {
    __builtin_amdgcn_global_load_lds((glb_u32*)g, (lds_u32*)l, 16, 0, 0);
}

// within-head permutation: perm(d) = (d&15)*4 + (d>>4);  inverse: d = (j>>2) + (j&3)*16

// ---------------- fused fp32 -> bf16 for x + 4 weight matrices ----------------
__global__ __launch_bounds__(256) void k_cvt5(const float* __restrict__ x, const float* __restrict__ wq,
                                              const float* __restrict__ wk, const float* __restrict__ wv,
                                              const float* __restrict__ wo, u16* __restrict__ xb,
                                              u16* __restrict__ wqb, u16* __restrict__ wkb,
                                              u16* __restrict__ wvb, u16* __restrict__ wob) {
    int sl = blockIdx.y;
    long e = (long)(blockIdx.x * 256 + threadIdx.x) * 4;
    if (sl == 5) {
        long n = e >> 11;
        int cin = (int)(e & 2047);
        int hd0 = (cin >> 6) * 64 + ((cin & 63) >> 2);
        const float* src = wo + n * 2048 + hd0;
        float f0 = src[0], f1 = src[16], f2 = src[32], f3 = src[48];
        uint2 o;
        o.x = pk2(f0, f1);
        o.y = pk2(f2, f3);
        *(uint2*)(wob + e) = o;
        return;
    }
    const float* s;
    u16* d;
    if (sl == 0) { s = x; d = xb; }
    else if (sl == 1) { s = x + 4194304; d = xb + 4194304; }
    else if (sl == 2) { s = wq; d = wqb; }
    else if (sl == 3) { s = wk; d = wkb; }
    else { s = wv; d = wvb; }
    float4 f = *(const float4*)(s + e);
    uint2 o;
    o.x = pk2(f.x, f.y);
    o.y = pk2(f.z, f.w);
    *(uint2*)(d + e) = o;
}

// ---------------- cos/sin tables ----------------
__global__ void k_trig(const float* __restrict__ pf, float* __restrict__ ct, float* __restrict__ st) {
    int i = blockIdx.x * 256 + threadIdx.x;  // 65536 = S*32
    float f = pf[i];
    ct[i] = cosf(f);
    st[i] = sinf(f);
}

// ---------------- permuted post-LN gamma/beta ----------------
__global__ void k_ppg(const float* __restrict__ pg, const float* __restrict__ pb,
                      float* __restrict__ pgp, float* __restrict__ pbp) {
    int i = blockIdx.x * 256 + threadIdx.x;  // 2048
    int h = i >> 6, o = i & 63;
    int src = h * 64 + (o >> 2) + (o & 3) * 16;
    pgp[i] = pg[src];
    pbp[i] = pb[src];
}

// ---------------- 8-phase 256x128 MFMA GEMM:  C[M,N] = A[M,K] * B[N,K]^T ----------------
// T2+T3+T4+T5 (learn_hip m201 template, adapted to 256x128 so grids are multiples of 256 CUs):
//  * BK=64, dbuf LDS (A 2x32KB, B 2x16KB = 96 KiB), 8 waves (2M x 4N), per-wave C = 128x32
//  * (row&7)<<4 byte-XOR swizzle: staging pre-swizzles the GLOBAL source (linear gload_lds
//    dest), reads XOR the same bits -> frag ds_read_b128 spread over all banks (2-way free)
//  * 8 phases per iter (2 K-tiles); counted vmcnt(2) ONLY at phases 4/8; never drained to 0
//  * setprio(1) around each 8-MFMA cluster; 2 raw s_barriers per phase
// EPI 0: fp32 store; EPI 1: RoPE + bf16 (B,H,S,HD); z==2 (V) permuted-only, z==0/1 dual store
#define VM2() asm volatile("s_waitcnt vmcnt(2)" ::: "memory")
#define BARR() asm volatile("s_barrier" ::: "memory")
#define STAGE_A(tau, hf)                                                                           \
    {                                                                                              \
        u16* dst = AS[(tau) & 1] + (hf) * 8192;                                                    \
        int tc = ((tau) < kT ? (tau) : kT - 1) << 6;                                               \
        _Pragma("unroll") for (int h2 = 0; h2 < 2; ++h2) {                                         \
            int chb = h2 * 512 + wid * 64;                                                         \
            int ch = chb + lane;                                                                   \
            int r = ch >> 3, c8 = ch & 7;                                                          \
            const u16* gp = A + (long)(m0 + (hf) * 128 + r) * K + tc + ((c8 ^ (r & 7)) << 3);      \
            async_copy16(gp, dst + chb * 8);                                                       \
        }                                                                                          \
    }
#define STAGE_B(tau, hf)                                                                           \
    {                                                                                              \
        u16* dst = BS[(tau) & 1] + (hf) * 4096;                                                    \
        int tc = ((tau) < kT ? (tau) : kT - 1) << 6;                                               \
        int chb = wid * 64;                                                                        \
        int ch = chb + lane;                                                                       \
        int r = ch >> 3, c8 = ch & 7;                                                              \
        const u16* gp = Bm + (long)(n0 + (hf) * 64 + r) * K + tc + ((c8 ^ (r & 7)) << 3);          \
        async_copy16(gp, dst + chb * 8);                                                           \
    }
#define LDA4(ab, miB)                                                                              \
    _Pragma("unroll") for (int q = 0; q < 4; ++q) _Pragma("unroll") for (int ks = 0; ks < 2; ++ks) { \
        int row = wm * 128 + ((miB) + q) * 16 + col16;                                             \
        int off = (row * 64 + ks * 32 + quad8) ^ ((row & 7) << 3);                                 \
        af[q][ks] = *(const bf16x8_t*)((ab) + off);                                                \
    }
#define LDB2(dst, bb, ni)                                                                          \
    _Pragma("unroll") for (int ks = 0; ks < 2; ++ks) {                                             \
        int row = wn * 32 + (ni) * 16 + col16;                                                     \
        int off = (row * 64 + ks * 32 + quad8) ^ ((row & 7) << 3);                                 \
        dst[ks] = *(const bf16x8_t*)((bb) + off);                                                  \
    }
#define MM8(mB, nI, b2)                                                                            \
    __builtin_amdgcn_s_setprio(1);                                                                 \
    _Pragma("unroll") for (int q = 0; q < 4; ++q) {                                                \
        acc[(mB) + q][nI] = MF(af[q][0], b2[0], acc[(mB) + q][nI]);                                \
        acc[(mB) + q][nI] = MF(af[q][1], b2[1], acc[(mB) + q][nI]);                                \
    }                                                                                              \
    __builtin_amdgcn_s_setprio(0);

template <int EPI>
__global__ __launch_bounds__(512, 2) void k_gemm256(const u16* __restrict__ A, const u16* __restrict__ B0,
                                                    const u16* __restrict__ B1, const u16* __restrict__ B2,
                                                    void* __restrict__ C0, void* __restrict__ C1,
                                                    void* __restrict__ C2, int M, int Nn, int K,
                                                    const float* __restrict__ ct, const float* __restrict__ st,
                                                    u16* __restrict__ P0, u16* __restrict__ P1) {
    __shared__ u16 AS[2][16384];  // [dbuf][256 rows][64 k]
    __shared__ u16 BS[2][8192];   // [dbuf][128 rows][64 k]
    const int z = blockIdx.z;
    const u16* Bm = (z == 0) ? B0 : (z == 1) ? B1 : B2;
    void* Cout = (z == 0) ? C0 : (z == 1) ? C1 : C2;
    u16* Pout = (z == 0) ? P0 : P1;
    const int tid = threadIdx.x, lane = tid & 63, wid = tid >> 6;
    const int wm = wid >> 2, wn = wid & 3;  // 2M x 4N waves
    const int col16 = lane & 15, quad8 = (lane >> 4) * 8;
    const int m0 = blockIdx.y * 256, n0 = blockIdx.x * 128;
    const int kT = K >> 6;       // 64-wide K tiles (32 for K=2048)
    const int ITERS = kT >> 1;   // 16

    f32x4_t acc[8][2];
    f32x4_t zero = {0.f, 0.f, 0.f, 0.f};
#pragma unroll
    for (int a = 0; a < 8; ++a) {
        acc[a][0] = zero;
        acc[a][1] = zero;
    }
    bf16x8_t af[4][2], bn0[2], bn1[2];

    // prologue: tile0 (A0,A1,B0,B1) + tile1 A0  -> 8 loads; wait 6 oldest (tile0)
    STAGE_A(0, 0);
    STAGE_A(0, 1);
    STAGE_B(0, 0);
    STAGE_B(0, 1);
    STAGE_A(1, 0);
    VM2();
    BARR();

    for (int i = 0; i < ITERS; ++i) {
        const int e = 2 * i, o = e + 1;
        const u16* a0b = AS[0];
        const u16* b0b = BS[0];
        const u16* a1b = AS[1];
        const u16* b1b = BS[1];
        // ---- phase 0 (tile e, buf0): read A[0-3]+B[ni0]; stage A1(o)
        LDA4(a0b, 0);
        LDB2(bn0, b0b, 0);
        STAGE_A(o, 1);
        BARR();
        MM8(0, 0, bn0);
        BARR();
        // ---- phase 1: read B[ni1]; stage B0(o)
        LDB2(bn1, b0b, 1);
        STAGE_B(o, 0);
        BARR();
        MM8(0, 1, bn1);
        BARR();
        // ---- phase 2: read A[4-7]; stage B1(o)
        LDA4(a0b, 4);
        STAGE_B(o, 1);
        BARR();
        MM8(4, 1, bn1);
        BARR();
        // ---- phase 3: stage A0(e+2); vmcnt(2) -> tile o fully landed
        STAGE_A(e + 2, 0);
        BARR();
        MM8(4, 0, bn0);
        VM2();
        BARR();
        // ---- phase 4 (tile o, buf1): read A[0-3]+B[ni0]; stage A1(e+2)
        LDA4(a1b, 0);
        LDB2(bn0, b1b, 0);
        STAGE_A(e + 2, 1);
        BARR();
        MM8(0, 0, bn0);
        BARR();
        // ---- phase 5: read B[ni1]; stage B0(e+2)
        LDB2(bn1, b1b, 1);
        STAGE_B(e + 2, 0);
        BARR();
        MM8(0, 1, bn1);
        BARR();
        // ---- phase 6: read A[4-7]; stage B1(e+2)
        LDA4(a1b, 4);
        STAGE_B(e + 2, 1);
        BARR();
        MM8(4, 1, bn1);
        BARR();
        // ---- phase 7: stage A0(o+2); vmcnt(2) -> tile e+2 fully landed
        STAGE_A(o + 2, 0);
        BARR();
        MM8(4, 0, bn0);
        VM2();
        BARR();
    }

    int rq = (lane >> 4) * 4;
#pragma unroll
    for (int mi = 0; mi < 8; ++mi) {
#pragma unroll
        for (int ni = 0; ni < 2; ++ni) {
#pragma unroll
            for (int r = 0; r < 4; ++r) {
                int gr = m0 + wm * 128 + mi * 16 + rq + r;
                int gc = n0 + wn * 32 + ni * 16 + col16;
                float val = acc[mi][ni][r];
                if (EPI == 0) {
                    ((float*)Cout)[(long)gr * Nn + gc] = val;
                } else {
                    // fused RoPE: pair partner sits on lane^1 (gc differs in bit 0)
                    int b = gr >> 11, s2 = gr & 2047, hh = gc >> 6, hd = gc & 63;
                    int fi = s2 * 32 + (hd >> 1);
                    float c = ct[fi], sn = st[fi];
                    float partner = __shfl_xor(val, 1);
                    float y = (gc & 1) ? (partner * sn + val * c) : (val * c - partner * sn);
                    u16 yb = f2b(y);
                    long rowb = (((long)(b * HH + hh) * SS) + s2) * HDD;
                    int po = (hd & 15) * 4 + (hd >> 4);
                    if (z == 2) {
                        ((u16*)Cout)[rowb + po] = yb;  // V: permuted only
                    } else {
                        ((u16*)Cout)[rowb + hd] = yb;  // std (A-frags)
                        Pout[rowb + po] = yb;          // permuted (C-layout raws)
                    }
                }
            }
        }
    }
}

// ---------------- ilr gate ----------------
__global__ __launch_bounds__(256) void k_lr(const u16* __restrict__ xb, const float* __restrict__ ilrW,
                                            const float* __restrict__ ilrb, float* __restrict__ lrout) {
    __shared__ u16 xr[4][2048];
    int row0 = blockIdx.x * 4;
    int tid = threadIdx.x, lane = tid & 63, wv = tid >> 6;
    const unsigned* src = (const unsigned*)(xb + row0 * 2048);
    unsigned* dst = (unsigned*)xr;
    for (int i = tid; i < 4096; i += 256) dst[i] = src[i];
    __syncthreads();
    int b = row0 >> 11, s0 = row0 & 2047;
#pragma unroll
    for (int sub = 0; sub < 8; ++sub) {
        int h = wv * 8 + sub;
        const float* wp = ilrW + h * 2048;
        float a0 = 0.f, a1 = 0.f, a2 = 0.f, a3 = 0.f;
        for (int i = 0; i < 16; ++i) {
            int idx = i * 128 + lane * 2;
            float2 w2 = *(const float2*)(wp + idx);
            unsigned p0 = *(const unsigned*)&xr[0][idx];
            unsigned p1 = *(const unsigned*)&xr[1][idx];
            unsigned p2 = *(const unsigned*)&xr[2][idx];
            unsigned p3 = *(const unsigned*)&xr[3][idx];
            a0 += b2f((u16)p0) * w2.x + b2f((u16)(p0 >> 16)) * w2.y;
            a1 += b2f((u16)p1) * w2.x + b2f((u16)(p1 >> 16)) * w2.y;
            a2 += b2f((u16)p2) * w2.x + b2f((u16)(p2 >> 16)) * w2.y;
            a3 += b2f((u16)p3) * w2.x + b2f((u16)(p3 >> 16)) * w2.y;
        }
        a0 = wsum(a0);
        a1 = wsum(a1);
        a2 = wsum(a2);
        a3 = wsum(a3);
        if (lane == 0) {
            float bv = ilrb[h];
            float* op = lrout + ((b * HH + h) * SS) + s0;
            op[0] = (1.0f / (1.0f + expf(-(a0 + bv)))) * (1.0f / 64.0f);
            op[1] = (1.0f / (1.0f + expf(-(a1 + bv)))) * (1.0f / 64.0f);
            op[2] = (1.0f / (1.0f + expf(-(a2 + bv)))) * (1.0f / 64.0f);
            op[3] = (1.0f / (1.0f + expf(-(a3 + bv)))) * (1.0f / 64.0f);
        }
    }
}

// ---------------- TTT scan: ONE WAVE per (b,h) ----------------
// (unchanged from round 8: K=16 MFMAs in-register, DPP reduces, wide prefetch-at-top)
__global__ __launch_bounds__(64, 1) void k_scan(const u16* __restrict__ qb, const u16* __restrict__ kb2,
                                                const u16* __restrict__ qpc, const u16* __restrict__ kpc,
                                                const u16* __restrict__ vc, const float* __restrict__ lrbuf,
                                                const float* __restrict__ lgs, const float* __restrict__ tg,
                                                const float* __restrict__ tb, const float* __restrict__ W0,
                                                const float* __restrict__ b0, u16* __restrict__ ys) {
    __shared__ u16 WbL[64 * 72];  // [d2][d1] bf16 W for next step's B-frags

    const int bh = blockIdx.x, h = bh & 31, b = bh >> 5;
    const int lane = threadIdx.x & 63;
    const int quad = lane >> 4, col = lane & 15;
    const int base = bh * SS;

    float gd4[4], bd4[4], bbv[4], g2[4], gb[4];
#pragma unroll
    for (int tn = 0; tn < 4; ++tn) {
        gd4[tn] = tg[h * 64 + tn * 16 + col];
        bd4[tn] = tb[h * 64 + tn * 16 + col];
        bbv[tn] = b0[h * 64 + tn * 16 + col];
        g2[tn] = gd4[tn] * gd4[tn];
        gb[tn] = gd4[tn] * bd4[tn];
    }
    float G2m;  // mean over d of gamma^2
    {
        float s = g2[0] + g2[1] + g2[2] + g2[3];
        s = rsum16(s);
        G2m = s * (1.f / 64.f);
    }
    const float gs15 = fmaxf(1.f / 16.f + lgs[15], 0.f);
    const float inv15 = gs15 > 0.f ? 1.f / gs15 : 0.f;
    float gs4[4], ratio4[4];
#pragma unroll
    for (int r = 0; r < 4; ++r) {
        int i = quad * 4 + r;
        gs4[r] = fmaxf(1.f / (float)(i + 1) + lgs[i], 0.f);
        ratio4[r] = gs4[r] * inv15;
    }

    f32x4_t Wc[4][4];
#pragma unroll
    for (int tm = 0; tm < 4; ++tm)
#pragma unroll
        for (int tn = 0; tn < 4; ++tn)
#pragma unroll
            for (int r = 0; r < 4; ++r)
                Wc[tm][tn][r] = W0[h * 4096 + (tm * 16 + quad * 4 + r) * 64 + tn * 16 + col];

    {  // initial Wb
        unsigned* wb32 = (unsigned*)WbL;
#pragma unroll
        for (int tn = 0; tn < 4; ++tn)
#pragma unroll
            for (int tm = 0; tm < 4; ++tm) {
                int a = (tn * 16 + col) * 36 + tm * 8 + quad * 2;  // u32 units; row stride 36 u32
                wb32[a] = cvtpk(Wc[tm][tn][0], Wc[tm][tn][1]);
                wb32[a + 1] = cvtpk(Wc[tm][tn][2], Wc[tm][tn][3]);
            }
    }

    // prefetch chunk 0 (lr pre-scaled by -gs15)
    bf16x8_t ka[2], qa[2];
    float lr4[4];
    u16 kraw[16], vraw[16], qraw[16];
    {
        const u16* kp = kb2 + (base + col) * 64;
        const u16* qp = qb + (base + col) * 64;
#pragma unroll
        for (int kh = 0; kh < 2; ++kh) {
            ka[kh] = *(const bf16x8_t*)(kp + kh * 32 + quad * 8);
            qa[kh] = *(const bf16x8_t*)(qp + kh * 32 + quad * 8);
        }
#pragma unroll
        for (int r = 0; r < 4; ++r) lr4[r] = -gs15 * lrbuf[base + quad * 4 + r];
#pragma unroll
        for (int r = 0; r < 4; ++r) {
            long ro = (long)(base + quad * 4 + r) * 64 + col * 4;
            ushort4 tk = *(const ushort4*)(kpc + ro);
            ushort4 tv = *(const ushort4*)(vc + ro);
            ushort4 tq = *(const ushort4*)(qpc + ro);
            kraw[r] = tk.x; kraw[4 + r] = tk.y; kraw[8 + r] = tk.z; kraw[12 + r] = tk.w;
            vraw[r] = tv.x; vraw[4 + r] = tv.y; vraw[8 + r] = tv.z; vraw[12 + r] = tv.w;
            qraw[r] = tq.x; qraw[4 + r] = tq.y; qraw[8 + r] = tq.z; qraw[12 + r] = tq.w;
        }
    }

    // prologue: wbf(0) read
    bf16x8_t wbf[4][2];
#pragma unroll
    for (int tn = 0; tn < 4; ++tn)
#pragma unroll
        for (int kh = 0; kh < 2; ++kh)
            wbf[tn][kh] = *(const bf16x8_t*)&WbL[(tn * 16 + col) * 72 + kh * 32 + quad * 8];

    const f32x4_t zf = {0.f, 0.f, 0.f, 0.f};

    for (int n = 0; n < NN; ++n) {
        const int s0 = n * 16;

        // prefetch next chunk FIRST (loads issue before the wbf lgkm wait)
        bf16x8_t nka[2], nqa[2];
        float nlr[4];
        u16 nkraw[16], nvraw[16], nqraw[16];
        {
            const int sp = (n + 1 < NN) ? s0 + 16 : s0;
            const u16* kp = kb2 + (base + sp + col) * 64;
            const u16* qp = qb + (base + sp + col) * 64;
#pragma unroll
            for (int kh = 0; kh < 2; ++kh) {
                nka[kh] = *(const bf16x8_t*)(kp + kh * 32 + quad * 8);
                nqa[kh] = *(const bf16x8_t*)(qp + kh * 32 + quad * 8);
            }
#pragma unroll
            for (int r = 0; r < 4; ++r) nlr[r] = -gs15 * lrbuf[base + sp + quad * 4 + r];
#pragma unroll
            for (int r = 0; r < 4; ++r) {
                long ro = (long)(base + sp + quad * 4 + r) * 64 + col * 4;
                ushort4 tk = *(const ushort4*)(kpc + ro);
                ushort4 tv = *(const ushort4*)(vc + ro);
                ushort4 tq = *(const ushort4*)(qpc + ro);
                nkraw[r] = tk.x; nkraw[4 + r] = tk.y; nkraw[8 + r] = tk.z; nkraw[12 + r] = tk.w;
                nvraw[r] = tv.x; nvraw[4 + r] = tv.y; nvraw[8 + r] = tv.z; nvraw[12 + r] = tv.w;
                nqraw[r] = tq.x; nqraw[4 + r] = tq.y; nqraw[8 + r] = tq.z; nqraw[12 + r] = tq.w;
            }
        }

        // Z = XK@W + bb, XQW = XQ@W + bb (bb as MFMA C-init), AttnT = XK@XQ^T
        f32x4_t z[4], xqw[4], attnT;
#pragma unroll
        for (int tn = 0; tn < 4; ++tn) {
            f32x4_t cb = {bbv[tn], bbv[tn], bbv[tn], bbv[tn]};
            z[tn] = MF(ka[1], wbf[tn][1], cb);
            z[tn] = MF(ka[0], wbf[tn][0], z[tn]);
            xqw[tn] = MF(qa[1], wbf[tn][1], cb);
            xqw[tn] = MF(qa[0], wbf[tn][0], xqw[tn]);
        }
        attnT = MF(ka[1], qa[1], zf);
        attnT = MF(ka[0], qa[0], attnT);

        // lane holds Attn[i=col][j=quad*4+r]; tril mask j<=i, in-register Pu A-frag
        float pv0 = (quad * 4 + 0 <= col) ? (1.f + attnT[0]) : 0.f;
        float pv1 = (quad * 4 + 1 <= col) ? (1.f + attnT[1]) : 0.f;
        float pv2 = (quad * 4 + 2 <= col) ? (1.f + attnT[2]) : 0.f;
        float pv3 = (quad * 4 + 3 <= col) ? (1.f + attnT[3]) : 0.f;
        bf16x4_t pa4 = mk4(cvtpk(pv0, pv1), cvtpk(pv2, pv3));

        // fused ln_l2_bwd: single DPP reduce phase over 6 sums (z already includes bb)
        float c1[16];
        float A1[4], A2[4], A3[4], A4[4], A5[4], A6[4];
#pragma unroll
        for (int r = 0; r < 4; ++r) { A1[r] = 0.f; A2[r] = 0.f; A3[r] = 0.f; A4[r] = 0.f; A5[r] = 0.f; A6[r] = 0.f; }
#pragma unroll
        for (int tn = 0; tn < 4; ++tn)
#pragma unroll
            for (int r = 0; r < 4; ++r) {
                float zv = z[tn][r];
                float tgt = b2f(vraw[tn * 4 + r]) - b2f(kraw[tn * 4 + r]);
                float c = gb[tn] - gd4[tn] * tgt;  // g*(b - tgt)
                c1[tn * 4 + r] = c;
                float t = g2[tn] * zv;
                A1[r] += zv;
                A2[r] = fmaf(zv, zv, A2[r]);
                A3[r] += t;
                A4[r] = fmaf(t, zv, A4[r]);
                A5[r] = fmaf(c, zv, A5[r]);
                A6[r] += c;
            }
#pragma unroll
        for (int r = 0; r < 4; ++r) {
            A1[r] = rsum16(A1[r]);
            A2[r] = rsum16(A2[r]);
            A3[r] = rsum16(A3[r]);
            A4[r] = rsum16(A4[r]);
            A5[r] = rsum16(A5[r]);
            A6[r] = rsum16(A6[r]);
        }
        float mu4[4], rstd4[4], m1[4], m2[4], rl[4];
#pragma unroll
        for (int r = 0; r < 4; ++r) {
            float mu = A1[r] * (1.f / 64.f);
            float var = A2[r] * (1.f / 64.f) - mu * mu;
            float rstd = rsqrtf(var + 1e-5f);
            float T1m = A3[r] * (1.f / 64.f);
            float T2m = A4[r] * (1.f / 64.f);
            float T3m = A5[r] * (1.f / 64.f);
            float C1m = A6[r] * (1.f / 64.f);
            m1[r] = rstd * (T1m - mu * G2m) + C1m;
            m2[r] = rstd * rstd * (T2m - 2.f * mu * T1m + mu * mu * G2m) + rstd * (T3m - mu * C1m);
            mu4[r] = mu;
            rstd4[r] = rstd;
            rl[r] = rstd * lr4[r];  // includes -gs15
        }
        // gS' = -gs15 * lr * grad  (C-layout, feeds W-MFMA directly)
        float gS[4][4];
#pragma unroll
        for (int tn = 0; tn < 4; ++tn)
#pragma unroll
            for (int r = 0; r < 4; ++r) {
                float zh = (z[tn][r] - mu4[r]) * rstd4[r];
                float dzh = fmaf(g2[tn], zh, c1[tn * 4 + r]);
                gS[tn][r] = fmaf(-m2[r], zh, dzh - m1[r]) * rl[r];
            }
        // in-register B-frags (G') and A-frags (XKT)
        bf16x4_t gsB[4], xk4[4];
#pragma unroll
        for (int tn = 0; tn < 4; ++tn) {
            gsB[tn] = mk4(cvtpk(gS[tn][0], gS[tn][1]), cvtpk(gS[tn][2], gS[tn][3]));
            xk4[tn] = mk4(pk2r(kraw[tn * 4 + 0], kraw[tn * 4 + 1]), pk2r(kraw[tn * 4 + 2], kraw[tn * 4 + 3]));
        }

        // W update: Wc += XKT @ G'  (G' pre-scaled by -gs15) — pure MFMA accumulate
#pragma unroll
        for (int tm = 0; tm < 4; ++tm)
#pragma unroll
            for (int tn = 0; tn < 4; ++tn)
                Wc[tm][tn] = MFMA16(xk4[tm], gsB[tn], Wc[tm][tn]);
        {
            unsigned* wb32 = (unsigned*)WbL;
#pragma unroll
            for (int tn = 0; tn < 4; ++tn)
#pragma unroll
                for (int tm = 0; tm < 4; ++tm) {
                    int a = (tn * 16 + col) * 36 + tm * 8 + quad * 2;
                    wb32[a] = cvtpk(Wc[tm][tn][0], Wc[tm][tn][1]);
                    wb32[a + 1] = cvtpk(Wc[tm][tn][2], Wc[tm][tn][3]);
                }
        }

        // Z_bar = XQW(+bb) + ratio * (Pu @ G')
#pragma unroll
        for (int tn = 0; tn < 4; ++tn) {
            f32x4_t pg = MFMA16(pa4, gsB[tn], zf);
#pragma unroll
            for (int r = 0; r < 4; ++r) z[tn][r] = fmaf(ratio4[r], pg[r], xqw[tn][r]);
        }
        // y = XQ + ln_fwd(Z_bar)  -> bf16 (permuted layout, uint2 store)
#pragma unroll
        for (int r = 0; r < 4; ++r) {
            float s1 = z[0][r] + z[1][r] + z[2][r] + z[3][r];
            float s2 = z[0][r] * z[0][r] + z[1][r] * z[1][r] + z[2][r] * z[2][r] + z[3][r] * z[3][r];
            s1 = rsum16(s1);
            s2 = rsum16(s2);
            float mu = s1 * (1.f / 64.f);
            float var = s2 * (1.f / 64.f) - mu * mu;
            mu4[r] = mu;
            rstd4[r] = rsqrtf(var + 1e-5f);
        }
#pragma unroll
        for (int r = 0; r < 4; ++r) {
            float y0 = b2f(qraw[0 * 4 + r]) + gd4[0] * (z[0][r] - mu4[r]) * rstd4[r] + bd4[0];
            float y1 = b2f(qraw[1 * 4 + r]) + gd4[1] * (z[1][r] - mu4[r]) * rstd4[r] + bd4[1];
            float y2 = b2f(qraw[2 * 4 + r]) + gd4[2] * (z[2][r] - mu4[r]) * rstd4[r] + bd4[2];
            float y3 = b2f(qraw[3 * 4 + r]) + gd4[3] * (z[3][r] - mu4[r]) * rstd4[r] + bd4[3];
            uint2 po;
            po.x = cvtpk(y0, y1);
            po.y = cvtpk(y2, y3);
            *(uint2*)(ys + (long)(b * SS + s0 + quad * 4 + r) * DD + h * 64 + col * 4) = po;
        }

        // b update: bb += colsum(G')
#pragma unroll
        for (int tn = 0; tn < 4; ++tn) {
            float c = gS[tn][0] + gS[tn][1] + gS[tn][2] + gS[tn][3];
            c += __shfl_xor(c, 16);
            c += __shfl_xor(c, 32);
            bbv[tn] += c;
        }

        // hoisted: wbf(n+1) read (WbL writes above are in-wave ordered)
#pragma unroll
        for (int tn = 0; tn < 4; ++tn)
#pragma unroll
            for (int kh = 0; kh < 2; ++kh)
                wbf[tn][kh] = *(const bf16x8_t*)&WbL[(tn * 16 + col) * 72 + kh * 32 + quad * 8];

        ka[0] = nka[0]; ka[1] = nka[1];
        qa[0] = nqa[0]; qa[1] = nqa[1];
#pragma unroll
        for (int r = 0; r < 4; ++r) lr4[r] = nlr[r];
#pragma unroll
        for (int j = 0; j < 16; ++j) { kraw[j] = nkraw[j]; vraw[j] = nvraw[j]; qraw[j] = nqraw[j]; }
    }
}

// ---------------- post layernorm (bf16 in, PERMUTED space) -> bf16 out (permuted) ----------------
__global__ __launch_bounds__(256) void k_postln(const u16* __restrict__ ys, const float* __restrict__ pg,
                                                const float* __restrict__ pb, u16* __restrict__ outb) {
    __shared__ float red[8];
    int row = blockIdx.x, tid = threadIdx.x, lane = tid & 63, wv = tid >> 6;
    const u16* rp = ys + row * 2048 + tid * 8;
    uint4 pkd = *(const uint4*)rp;
    float v[8];
    v[0] = b2f((u16)pkd.x); v[1] = b2f((u16)(pkd.x >> 16));
    v[2] = b2f((u16)pkd.y); v[3] = b2f((u16)(pkd.y >> 16));
    v[4] = b2f((u16)pkd.z); v[5] = b2f((u16)(pkd.z >> 16));
    v[6] = b2f((u16)pkd.w); v[7] = b2f((u16)(pkd.w >> 16));
    float s1 = 0.f, s2 = 0.f;
#pragma unroll
    for (int i = 0; i < 8; ++i) { s1 += v[i]; s2 += v[i] * v[i]; }
    s1 = wsum(s1);
    s2 = wsum(s2);
    if (lane == 0) {
        red[wv] = s1;
        red[wv + 4] = s2;
    }
    __syncthreads();
    float S1 = red[0] + red[1] + red[2] + red[3];
    float S2 = red[4] + red[5] + red[6] + red[7];
    float mu = S1 * (1.f / 2048), var = S2 * (1.f / 2048) - mu * mu;
    float rstd = rsqrtf(var + 1e-5f);
    const float4 g0 = *(const float4*)(pg + tid * 8);
    const float4 g1 = *(const float4*)(pg + tid * 8 + 4);
    const float4 b0v = *(const float4*)(pb + tid * 8);
    const float4 b1v = *(const float4*)(pb + tid * 8 + 4);
    float o[8];
    o[0] = g0.x * (v[0] - mu) * rstd + b0v.x;
    o[1] = g0.y * (v[1] - mu) * rstd + b0v.y;
    o[2] = g0.z * (v[2] - mu) * rstd + b0v.z;
    o[3] = g0.w * (v[3] - mu) * rstd + b0v.w;
    o[4] = g1.x * (v[4] - mu) * rstd + b1v.x;
    o[5] = g1.y * (v[5] - mu) * rstd + b1v.y;
    o[6] = g1.z * (v[6] - mu) * rstd + b1v.z;
    o[7] = g1.w * (v[7] - mu) * rstd + b1v.w;
    uint4 po;
    po.x = pk2(o[0], o[1]);
    po.y = pk2(o[2], o[3]);
    po.z = pk2(o[4], o[5]);
    po.w = pk2(o[6], o[7]);
    *(uint4*)(outb + row * 2048 + tid * 8) = po;
}

extern "C" void kernel_launch(void* const* d_in, const int* in_sizes, int n_in,
                              void* d_out, int out_size, void* d_ws, size_t ws_size,
                              hipStream_t stream) {
    const float* x = (const float*)d_in[0];
    const float* pf = (const float*)d_in[1];
    const float* Wq = (const float*)d_in[2];
    const float* Wk = (const float*)d_in[3];
    const float* Wv = (const float*)d_in[4];
    const float* Wo = (const float*)d_in[5];
    const float* pg = (const float*)d_in[6];
    const float* pb = (const float*)d_in[7];
    const float* ilrW = (const float*)d_in[8];
    const float* ilrb = (const float*)d_in[9];
    const float* lgs = (const float*)d_in[10];
    const float* tg = (const float*)d_in[11];
    const float* tb = (const float*)d_in[12];
    const float* W0 = (const float*)d_in[13];
    const float* b0 = (const float*)d_in[14];
    float* out = (float*)d_out;
    char* ws = (char*)d_ws;

    // workspace layout
    u16* xbf = (u16*)(ws + 0);             // 16 MB  (reused as lnb later)
    u16* wqb = (u16*)(ws + 16777216);      // 8 MB
    u16* wkb = (u16*)(ws + 25165824);      // 8 MB
    u16* wvb = (u16*)(ws + 33554432);      // 8 MB
    u16* wob = (u16*)(ws + 41943040);      // 8 MB   (permuted k-columns)
    u16* qbuf = (u16*)(ws + 50331648);     // 16 MB  (std layout, RoPE'd)
    u16* kbuf = (u16*)(ws + 67108864);     // 16 MB  (std layout, RoPE'd)
    u16* vbuf = (u16*)(ws + 83886080);     // 16 MB  (PERMUTED layout, RoPE'd)
    float* ct = (float*)(ws + 100663296);  // 256 KB
    float* st = (float*)(ws + 100925440);  // 256 KB
    float* lrb = (float*)(ws + 101187584); // 512 KB
    u16* ysb = (u16*)(ws + 101711872);     // 16 MB (bf16, permuted space)
    float* pgp = (float*)(ws + 118489088); // 8 KB
    float* pbp = (float*)(ws + 118497280); // 8 KB
    u16* qpc = (u16*)(ws + 118505472);     // 16 MB (permuted q copy)
    u16* kpc = (u16*)(ws + 135282688);     // 16 MB (permuted k copy)
    u16* lnb = (u16*)(ws + 0);             // reuse xbf region (dead after QKV GEMMs + k_lr)

    k_cvt5<<<dim3(4096, 6), 256, 0, stream>>>(x, Wq, Wk, Wv, Wo, xbf, wqb, wkb, wvb, wob);
    k_trig<<<256, 256, 0, stream>>>(pf, ct, st);
    k_ppg<<<8, 256, 0, stream>>>(pg, pb, pgp, pbp);

    k_gemm256<1><<<dim3(16, 16, 3), 512, 0, stream>>>(xbf, wqb, wkb, wvb, qbuf, kbuf, vbuf,
                                                      4096, 2048, 2048, ct, st, qpc, kpc);

    k_lr<<<1024, 256, 0, stream>>>(xbf, ilrW, ilrb, lrb);

    k_scan<<<64, 64, 0, stream>>>(qbuf, kbuf, qpc, kpc, vbuf, lrb, lgs, tg, tb, W0, b0, ysb);

    k_postln<<<4096, 256, 0, stream>>>(ysb, pgp, pbp, lnb);
    k_gemm256<0><<<dim3(16, 16, 1), 512, 0, stream>>>(lnb, wob, wob, wob, out, out, out,
                                                      4096, 2048, 2048, nullptr, nullptr, nullptr, nullptr);
}